// Round 8
// baseline (159.699 us; speedup 1.0000x reference)
//
#include <hip/hip_runtime.h>
#include <hip/hip_bf16.h>
#include <stdint.h>

// Problem constants
#define B_ 4
#define L_ 1024
#define D_ 768
#define H_ 12
#define HD_ 64
#define M_ 4096     // B*L
#define N3_ 2304    // 3*D

typedef float f32x4 __attribute__((ext_vector_type(4)));
typedef float f32x4v __attribute__((ext_vector_type(4)));
typedef short bf16x8 __attribute__((ext_vector_type(8)));
typedef unsigned short u16;
typedef u16 u16x8 __attribute__((ext_vector_type(8)));
typedef u16 u16x4 __attribute__((ext_vector_type(4)));
typedef uint32_t u32x2 __attribute__((ext_vector_type(2)));

#define AS3 __attribute__((address_space(3)))
#define AS1 __attribute__((address_space(1)))

__device__ __forceinline__ void gll16(const void* g, void* l) {
  __builtin_amdgcn_global_load_lds((const AS1 void*)g, (AS3 void*)l, 16, 0, 0);
}

// fp32 -> bf16 round-to-nearest-even (finite data)
__device__ __forceinline__ u16 f2bf(float f) {
  uint32_t u = __builtin_bit_cast(uint32_t, f);
  u += 0x7fffu + ((u >> 16) & 1u);
  return (u16)(u >> 16);
}

// ---------------- fused conversion kernel (3 tensors, fp32 -> bf16) ---------
__global__ void k_cvt3(const float* __restrict__ a, u16* __restrict__ ao, int na4,
                       const float* __restrict__ b, u16* __restrict__ bo, int nb4,
                       const float* __restrict__ c, u16* __restrict__ co, int nc4) {
  int i = blockIdx.x * 256 + threadIdx.x;
  const float* src;
  u16* dst;
  if (i < na4) {
    src = a; dst = ao;
  } else if (i < na4 + nb4) {
    src = b; dst = bo; i -= na4;
  } else if (i < na4 + nb4 + nc4) {
    src = c; dst = co; i -= na4 + nb4;
  } else {
    return;
  }
  f32x4v v = ((const f32x4v*)src)[i];
  u16x4 o;
  o.x = f2bf(v.x); o.y = f2bf(v.y); o.z = f2bf(v.z); o.w = f2bf(v.w);
  ((u16x4*)dst)[i] = o;
}

// ---------------- GEMM1: qkv = x @ w_in^T + b_in -> Q,K,V bf16 [B,H,L,64] ----
__global__ __launch_bounds__(256) void k_gemm_qkv(
    const u16* __restrict__ Xb, const u16* __restrict__ Wb,
    const float* __restrict__ b_in,
    u16* __restrict__ gQ, u16* __restrict__ gK, u16* __restrict__ gV) {
  __shared__ u16 As[128 * 64];
  __shared__ u16 Bs[128 * 64];
  const int tid = threadIdx.x;
  const int lane = tid & 63;
  const int w = tid >> 6;
  const int wm = (w >> 1) * 64;
  const int wn = (w & 1) * 64;
  const int lr = lane & 15;
  const int lg = lane >> 4;
  const int m0 = blockIdx.x * 128;
  const int n0 = blockIdx.y * 128;

  f32x4 acc[4][4];
#pragma unroll
  for (int i = 0; i < 4; ++i)
#pragma unroll
    for (int j = 0; j < 4; ++j) acc[i][j] = (f32x4){0.f, 0.f, 0.f, 0.f};

  for (int kt = 0; kt < 12; ++kt) {
    __syncthreads();
#pragma unroll
    for (int i = 0; i < 4; ++i) {
      int seg = i * 256 + tid;
      int row = seg >> 3;
      int sl = (seg & 7) ^ (row & 7);
      gll16(Xb + (size_t)(m0 + row) * 768 + kt * 64 + sl * 8, (char*)As + seg * 16);
      gll16(Wb + (size_t)(n0 + row) * 768 + kt * 64 + sl * 8, (char*)Bs + seg * 16);
    }
    __syncthreads();
#pragma unroll
    for (int kh = 0; kh < 2; ++kh) {
      bf16x8 af[4], bfr[4];
#pragma unroll
      for (int t = 0; t < 4; ++t) {
        int ra = wm + t * 16 + lr;
        af[t] = *(const bf16x8*)((const char*)As + ra * 128 +
                                 ((kh * 64 + lg * 16) ^ ((ra & 7) << 4)));
        int rb = wn + t * 16 + lr;
        bfr[t] = *(const bf16x8*)((const char*)Bs + rb * 128 +
                                  ((kh * 64 + lg * 16) ^ ((rb & 7) << 4)));
      }
#pragma unroll
      for (int mi = 0; mi < 4; ++mi)
#pragma unroll
        for (int ni = 0; ni < 4; ++ni)
          acc[mi][ni] = __builtin_amdgcn_mfma_f32_16x16x32_bf16(
              af[mi], bfr[ni], acc[mi][ni], 0, 0, 0);
    }
  }
  // epilogue: +b_in, scale q, scatter to [B,H,L,64] bf16
  const int sec = blockIdx.y / 6;  // 0=q,1=k,2=v
  u16* dst = sec == 0 ? gQ : (sec == 1 ? gK : gV);
  const float scale = sec == 0 ? 0.125f : 1.0f;
#pragma unroll
  for (int ni = 0; ni < 4; ++ni) {
    int e = n0 + wn + ni * 16 + lr;  // 0..2303
    float bias = b_in[e];
    int es = e - sec * 768;
    int h = es >> 6, d = es & 63;
#pragma unroll
    for (int mi = 0; mi < 4; ++mi) {
#pragma unroll
      for (int j = 0; j < 4; ++j) {
        int m = m0 + wm + mi * 16 + lg * 4 + j;
        int bb = m >> 10, lq = m & 1023;
        float vv = (acc[mi][ni][j] + bias) * scale;
        dst[(size_t)((bb * 12 + h) * 1024 + lq) * 64 + d] = f2bf(vv);
      }
    }
  }
}

// ---------------- V transpose: [B,H,L,64] -> [B,H,64,L] ---------------------
__global__ __launch_bounds__(256) void k_transpose(const u16* __restrict__ V,
                                                   u16* __restrict__ Vt) {
  __shared__ u16 t[64][66];
  const int tid = threadIdx.x;
  const int bh = blockIdx.x >> 4;
  const int kv0 = (blockIdx.x & 15) * 64;
  {
    int r = tid >> 2, c0 = (tid & 3) * 16;
    const u16* src = V + (size_t)(bh * 1024 + kv0 + r) * 64 + c0;
#pragma unroll
    for (int p = 0; p < 2; ++p) {
      u16x8 x = *(const u16x8*)(src + p * 8);
#pragma unroll
      for (int e = 0; e < 8; ++e) t[r][c0 + p * 8 + e] = x[e];
    }
  }
  __syncthreads();
  {
    int d = tid >> 2, k0 = (tid & 3) * 16;
    u16* dst = Vt + (size_t)(bh * 64 + d) * 1024 + kv0 + k0;
#pragma unroll
    for (int p = 0; p < 2; ++p) {
      u16x8 o;
#pragma unroll
      for (int e = 0; e < 8; ++e) o[e] = t[k0 + p * 8 + e][d];
      *(u16x8*)(dst + p * 8) = o;
    }
  }
}

// ---------------- fused flash attention (all-gll16 + linear bias warm) ------
// R7 structure (K/V/bias staged via global_load_lds, double-buffered, one
// __syncthreads per tile) + NEW: linear bias warm prologue. The block's bias
// footprint bias[bh][q0:q0+64][:] is one CONTIGUOUS 256KB chunk; the 4 waves
// stream it linearly at block start (discarded via asm sink) so DRAM sees
// ~768 linear 256KB streams instead of ~50k scattered 256B-at-4KB-stride
// streams, and the per-tile staged reads then hit L3 (201MB < 256MB).
__global__ __launch_bounds__(256) void k_attn(
    const u16* __restrict__ gQ, const u16* __restrict__ gK,
    const u16* __restrict__ gVt, const float* __restrict__ gBias,
    u16* __restrict__ gO) {
  __shared__ u16 Ks[2][64 * 64];   // 16 KB  [kv][d] rows 128B, src pre-swizzled
  __shared__ u16 Vs[2][64 * 64];   // 16 KB  [d][kv]
  __shared__ float Bi[2][64 * 64]; // 32 KB  [q][kv] fp32, slot-swizzled
  __shared__ f32x4 PlV[4][128];    // 8 KB   per-wave P bounce
  const int tid = threadIdx.x;
  const int lane = tid & 63;
  const int w = tid >> 6;
  const int lr = lane & 15;
  const int lg = lane >> 4;
  // XCD-bijective swizzle: 768 = 8 XCDs x 96; the 16 q-blocks sharing one
  // (b,h)'s K/V land on one XCD -> K/V stay L2-resident.
  const int lb = (blockIdx.x & 7) * 96 + (blockIdx.x >> 3);
  const int bh = lb >> 4;
  const int q0 = (lb & 15) * 64;
  const int qr = q0 + w * 16;  // wave's q-row base; lane's q-row = qr + lr

// Stage one full tile (K 8KB + V 8KB + bias 16KB) via gll16.
#define STAGE(buf, kv0)                                                        \
  do {                                                                         \
    _Pragma("unroll") for (int i_ = 0; i_ < 2; ++i_) {                         \
      int seg_ = i_ * 256 + tid;                                               \
      int row_ = seg_ >> 3;                                                    \
      int sl_ = (seg_ & 7) ^ (row_ & 7);                                       \
      gll16(gK + (size_t)(bh * 1024 + (kv0) + row_) * 64 + sl_ * 8,            \
            (char*)Ks[buf] + seg_ * 16);                                       \
      gll16(gVt + (size_t)(bh * 64 + row_) * 1024 + (kv0) + sl_ * 8,           \
            (char*)Vs[buf] + seg_ * 16);                                       \
    }                                                                          \
    _Pragma("unroll") for (int i_ = 0; i_ < 4; ++i_) {                         \
      int seg_ = i_ * 256 + tid;                                               \
      int qrow_ = seg_ >> 4;                                                   \
      int c_ = (seg_ & 15) ^ (qrow_ & 7);                                      \
      gll16(gBias + (size_t)(bh * 1024 + q0 + qrow_) * 1024 + (kv0) + c_ * 4,  \
            (char*)Bi[buf] + seg_ * 16);                                       \
    }                                                                          \
  } while (0)

  // ---- linear bias warm: block's contiguous 256KB, 64 dwordx4 per lane ----
  {
    const float* wb = gBias + (size_t)(bh * 1024 + q0 + w * 16) * 1024;  // 64KB/wave
#pragma unroll 8
    for (int i = 0; i < 64; ++i) {
      f32x4 v = *(const f32x4*)((const char*)wb + i * 1024 + lane * 16);
      asm volatile("" ::"v"(v));  // keep the load, discard the value
    }
  }

  // Q as B-operand: rows q = qr+lr (pre-scaled by 1/8 in GEMM1)
  bf16x8 qa[2];
#pragma unroll
  for (int kh = 0; kh < 2; ++kh)
    qa[kh] = *(const bf16x8*)(gQ + (size_t)(bh * 1024 + qr + lr) * 64 + kh * 32 + lg * 8);

  f32x4 oacc[4];
#pragma unroll
  for (int dt = 0; dt < 4; ++dt) oacc[dt] = (f32x4){0.f, 0.f, 0.f, 0.f};
  float mrow = -1e30f, lrow = 0.f;

  char* plw = (char*)PlV[w];
  const int swz = (lr & 7) << 4;

  STAGE(0, 0);
  __syncthreads();  // vmcnt(0): warm + stage 0 landed

  for (int t = 0; t < 16; ++t) {
    const int cur = t & 1;
    if (t < 15) STAGE(cur ^ 1, (t + 1) * 64);  // in flight across whole tile

    // S^T = K Q^T : s[ni][j] = S[kv = ni*16+lg*4+j][q = qr+lr]
    f32x4 s[4];
#pragma unroll
    for (int ni = 0; ni < 4; ++ni) s[ni] = (f32x4){0.f, 0.f, 0.f, 0.f};
    __builtin_amdgcn_s_setprio(1);
#pragma unroll
    for (int kh = 0; kh < 2; ++kh)
#pragma unroll
      for (int ni = 0; ni < 4; ++ni) {
        int rk = ni * 16 + lr;
        bf16x8 kb = *(const bf16x8*)((const char*)Ks[cur] + rk * 128 +
                                     ((kh * 64 + lg * 16) ^ ((rk & 7) << 4)));
        s[ni] = __builtin_amdgcn_mfma_f32_16x16x32_bf16(kb, qa[kh], s[ni], 0, 0, 0);
      }
    __builtin_amdgcn_s_setprio(0);

    // + bias from LDS: lane needs bias[q=qr+lr][kv0 + ni*16 + lg*4 + j]
#pragma unroll
    for (int ni = 0; ni < 4; ++ni) {
      f32x4 bv = *(const f32x4*)((const char*)Bi[cur] + (w * 16 + lr) * 256 +
                                 (((ni * 4 + lg) ^ (lr & 7)) << 4));
      s[ni] += bv;
    }

    // lane-local online softmax for q-row (qr+lr)
    float mx0 = fmaxf(fmaxf(s[0][0], s[0][1]), fmaxf(s[0][2], s[0][3]));
    float mx1 = fmaxf(fmaxf(s[1][0], s[1][1]), fmaxf(s[1][2], s[1][3]));
    float mx2 = fmaxf(fmaxf(s[2][0], s[2][1]), fmaxf(s[2][2], s[2][3]));
    float mx3 = fmaxf(fmaxf(s[3][0], s[3][1]), fmaxf(s[3][2], s[3][3]));
    float vmax = fmaxf(fmaxf(mx0, mx1), fmaxf(mx2, mx3));
    vmax = fmaxf(vmax, __shfl_xor(vmax, 16));
    vmax = fmaxf(vmax, __shfl_xor(vmax, 32));
    float mnew = fmaxf(mrow, vmax);
    float al = __expf(mrow - mnew);
    mrow = mnew;
#pragma unroll
    for (int ni = 0; ni < 4; ++ni)
#pragma unroll
      for (int j = 0; j < 4; ++j) s[ni][j] = __expf(s[ni][j] - mnew);
    float r0 = (s[0][0] + s[0][1]) + (s[0][2] + s[0][3]);
    float r1 = (s[1][0] + s[1][1]) + (s[1][2] + s[1][3]);
    float r2 = (s[2][0] + s[2][1]) + (s[2][2] + s[2][3]);
    float r3 = (s[3][0] + s[3][1]) + (s[3][2] + s[3][3]);
    float rs = (r0 + r1) + (r2 + r3);
    rs += __shfl_xor(rs, 16);
    rs += __shfl_xor(rs, 32);
    lrow = lrow * al + rs;

    // broadcast al from lane (lr = q) to the oacc owners (q = lg*4+j)
    f32x4 av;
#pragma unroll
    for (int j = 0; j < 4; ++j) av[j] = __shfl(al, (lane & 48) | (lg * 4 + j));
#pragma unroll
    for (int dt = 0; dt < 4; ++dt) oacc[dt] *= av;

    // P pack -> per-wave swizzled LDS (b64), read back as A-fragment, PV
#pragma unroll
    for (int ni = 0; ni < 4; ++ni) {
      uint32_t w0 = (uint32_t)f2bf(s[ni][0]) | ((uint32_t)f2bf(s[ni][1]) << 16);
      uint32_t w1 = (uint32_t)f2bf(s[ni][2]) | ((uint32_t)f2bf(s[ni][3]) << 16);
      u32x2 pv = {w0, w1};
      *(u32x2*)(plw + lr * 128 + ((ni * 32 + lg * 8) ^ swz)) = pv;
    }
    __builtin_amdgcn_s_setprio(1);
#pragma unroll
    for (int kh = 0; kh < 2; ++kh) {
      bf16x8 pa = *(const bf16x8*)(plw + lr * 128 + ((kh * 64 + lg * 16) ^ swz));
#pragma unroll
      for (int dt = 0; dt < 4; ++dt) {
        int rv = dt * 16 + lr;
        bf16x8 vb = *(const bf16x8*)((const char*)Vs[cur] + rv * 128 +
                                     ((kh * 64 + lg * 16) ^ ((rv & 7) << 4)));
        oacc[dt] = __builtin_amdgcn_mfma_f32_16x16x32_bf16(pa, vb, oacc[dt], 0, 0, 0);
      }
    }
    __builtin_amdgcn_s_setprio(0);

    __syncthreads();  // vmcnt(0): stage(t+1) landed (issued a full tile ago)
  }

  // normalize + store O bf16 [B,L,D]; inv broadcast like al
  float inv = 1.0f / lrow;
  f32x4 iv;
#pragma unroll
  for (int j = 0; j < 4; ++j) iv[j] = __shfl(inv, (lane & 48) | (lg * 4 + j));
  const int bg = bh / 12, h = bh % 12;
#pragma unroll
  for (int j = 0; j < 4; ++j) {
    int row = qr + lg * 4 + j;
#pragma unroll
    for (int dt = 0; dt < 4; ++dt) {
      gO[(size_t)(bg * 1024 + row) * 768 + h * 64 + dt * 16 + lr] =
          f2bf(oacc[dt][j] * iv[j]);
    }
  }
#undef STAGE
}

// ---------------- GEMM2: out = O @ w_out^T + b_out (fp32 out), 64x64 tiles --
__global__ __launch_bounds__(256) void k_gemm_out(
    const u16* __restrict__ Ob, const u16* __restrict__ Wb,
    const float* __restrict__ b_out, float* __restrict__ out) {
  __shared__ u16 As[64 * 64];
  __shared__ u16 Bs[64 * 64];
  const int tid = threadIdx.x;
  const int lane = tid & 63;
  const int w = tid >> 6;
  const int wm = (w >> 1) * 32;
  const int wn = (w & 1) * 32;
  const int lr = lane & 15;
  const int lg = lane >> 4;
  const int m0 = blockIdx.x * 64;
  const int n0 = blockIdx.y * 64;

  f32x4 acc[2][2];
#pragma unroll
  for (int i = 0; i < 2; ++i)
#pragma unroll
    for (int j = 0; j < 2; ++j) acc[i][j] = (f32x4){0.f, 0.f, 0.f, 0.f};

  for (int kt = 0; kt < 12; ++kt) {
    __syncthreads();
#pragma unroll
    for (int i = 0; i < 2; ++i) {
      int seg = i * 256 + tid;
      int row = seg >> 3;
      int sl = (seg & 7) ^ (row & 7);
      gll16(Ob + (size_t)(m0 + row) * 768 + kt * 64 + sl * 8, (char*)As + seg * 16);
      gll16(Wb + (size_t)(n0 + row) * 768 + kt * 64 + sl * 8, (char*)Bs + seg * 16);
    }
    __syncthreads();
#pragma unroll
    for (int kh = 0; kh < 2; ++kh) {
      bf16x8 af[2], bfr[2];
#pragma unroll
      for (int t = 0; t < 2; ++t) {
        int ra = wm + t * 16 + lr;
        af[t] = *(const bf16x8*)((const char*)As + ra * 128 +
                                 ((kh * 64 + lg * 16) ^ ((ra & 7) << 4)));
        int rb = wn + t * 16 + lr;
        bfr[t] = *(const bf16x8*)((const char*)Bs + rb * 128 +
                                  ((kh * 64 + lg * 16) ^ ((rb & 7) << 4)));
      }
#pragma unroll
      for (int mi = 0; mi < 2; ++mi)
#pragma unroll
        for (int ni = 0; ni < 2; ++ni)
          acc[mi][ni] = __builtin_amdgcn_mfma_f32_16x16x32_bf16(
              af[mi], bfr[ni], acc[mi][ni], 0, 0, 0);
    }
  }
#pragma unroll
  for (int ni = 0; ni < 2; ++ni) {
    int n = n0 + wn + ni * 16 + lr;
    float bias = b_out[n];
#pragma unroll
    for (int mi = 0; mi < 2; ++mi) {
#pragma unroll
      for (int j = 0; j < 4; ++j) {
        int m = m0 + wm + mi * 16 + lg * 4 + j;
        out[(size_t)m * 768 + n] = acc[mi][ni][j] + bias;
      }
    }
  }
}

extern "C" void kernel_launch(void* const* d_in, const int* in_sizes, int n_in,
                              void* d_out, int out_size, void* d_ws, size_t ws_size,
                              hipStream_t stream) {
  const float* x = (const float*)d_in[0];
  const float* attn_bias = (const float*)d_in[1];
  const float* w_in = (const float*)d_in[2];
  const float* b_in = (const float*)d_in[3];
  const float* w_out = (const float*)d_in[4];
  const float* b_out = (const float*)d_in[5];
  float* out = (float*)d_out;

  char* ws = (char*)d_ws;
  size_t off = 0;
  u16* xb = (u16*)(ws + off);  off += (size_t)M_ * D_ * 2;
  u16* wib = (u16*)(ws + off); off += (size_t)N3_ * D_ * 2;
  u16* wob = (u16*)(ws + off); off += (size_t)D_ * D_ * 2;
  u16* q = (u16*)(ws + off);   off += (size_t)48 * 1024 * 64 * 2;
  u16* k = (u16*)(ws + off);   off += (size_t)48 * 1024 * 64 * 2;
  u16* v = (u16*)(ws + off);   off += (size_t)48 * 1024 * 64 * 2;
  u16* vt = (u16*)(ws + off);  off += (size_t)48 * 1024 * 64 * 2;
  u16* ob = (u16*)(ws + off);  off += (size_t)M_ * D_ * 2;

  const int na4 = (M_ * D_) / 4;
  const int nb4 = (N3_ * D_) / 4;
  const int nc4 = (D_ * D_) / 4;
  k_cvt3<<<(na4 + nb4 + nc4 + 255) / 256, 256, 0, stream>>>(
      x, xb, na4, w_in, wib, nb4, w_out, wob, nc4);
  k_gemm_qkv<<<dim3(32, 18), 256, 0, stream>>>(xb, wib, b_in, q, k, v);
  k_transpose<<<768, 256, 0, stream>>>(v, vt);
  k_attn<<<768, 256, 0, stream>>>(q, k, vt, attn_bias, ob);
  k_gemm_out<<<dim3(64, 12), 256, 0, stream>>>(ob, wob, b_out, out);
}

// Round 9
// 123.785 us; speedup vs baseline: 1.2901x; 1.2901x over previous
//
#include <hip/hip_runtime.h>
#include <hip/hip_bf16.h>
#include <stdint.h>

// Problem constants
#define B_ 4
#define L_ 1024
#define D_ 768
#define H_ 12
#define HD_ 64
#define M_ 4096     // B*L
#define N3_ 2304    // 3*D

typedef float f32x4 __attribute__((ext_vector_type(4)));
typedef float f32x4v __attribute__((ext_vector_type(4)));
typedef short bf16x8 __attribute__((ext_vector_type(8)));
typedef unsigned short u16;
typedef u16 u16x8 __attribute__((ext_vector_type(8)));
typedef u16 u16x4 __attribute__((ext_vector_type(4)));
typedef uint32_t u32x2 __attribute__((ext_vector_type(2)));

#define AS3 __attribute__((address_space(3)))
#define AS1 __attribute__((address_space(1)))

__device__ __forceinline__ void gll16(const void* g, void* l) {
  __builtin_amdgcn_global_load_lds((const AS1 void*)g, (AS3 void*)l, 16, 0, 0);
}

// fp32 -> bf16 round-to-nearest-even (finite data)
__device__ __forceinline__ u16 f2bf(float f) {
  uint32_t u = __builtin_bit_cast(uint32_t, f);
  u += 0x7fffu + ((u >> 16) & 1u);
  return (u16)(u >> 16);
}

// ---------------- fused conversion kernel (3 tensors, fp32 -> bf16) ---------
__global__ void k_cvt3(const float* __restrict__ a, u16* __restrict__ ao, int na4,
                       const float* __restrict__ b, u16* __restrict__ bo, int nb4,
                       const float* __restrict__ c, u16* __restrict__ co, int nc4) {
  int i = blockIdx.x * 256 + threadIdx.x;
  const float* src;
  u16* dst;
  if (i < na4) {
    src = a; dst = ao;
  } else if (i < na4 + nb4) {
    src = b; dst = bo; i -= na4;
  } else if (i < na4 + nb4 + nc4) {
    src = c; dst = co; i -= na4 + nb4;
  } else {
    return;
  }
  f32x4v v = ((const f32x4v*)src)[i];
  u16x4 o;
  o.x = f2bf(v.x); o.y = f2bf(v.y); o.z = f2bf(v.z); o.w = f2bf(v.w);
  ((u16x4*)dst)[i] = o;
}

// ---------------- GEMM1: qkv = x @ w_in^T + b_in -> Q,K,V bf16 [B,H,L,64] ----
__global__ __launch_bounds__(256) void k_gemm_qkv(
    const u16* __restrict__ Xb, const u16* __restrict__ Wb,
    const float* __restrict__ b_in,
    u16* __restrict__ gQ, u16* __restrict__ gK, u16* __restrict__ gV) {
  __shared__ u16 As[128 * 64];
  __shared__ u16 Bs[128 * 64];
  const int tid = threadIdx.x;
  const int lane = tid & 63;
  const int w = tid >> 6;
  const int wm = (w >> 1) * 64;
  const int wn = (w & 1) * 64;
  const int lr = lane & 15;
  const int lg = lane >> 4;
  const int m0 = blockIdx.x * 128;
  const int n0 = blockIdx.y * 128;

  f32x4 acc[4][4];
#pragma unroll
  for (int i = 0; i < 4; ++i)
#pragma unroll
    for (int j = 0; j < 4; ++j) acc[i][j] = (f32x4){0.f, 0.f, 0.f, 0.f};

  for (int kt = 0; kt < 12; ++kt) {
    __syncthreads();
#pragma unroll
    for (int i = 0; i < 4; ++i) {
      int seg = i * 256 + tid;
      int row = seg >> 3;
      int sl = (seg & 7) ^ (row & 7);
      gll16(Xb + (size_t)(m0 + row) * 768 + kt * 64 + sl * 8, (char*)As + seg * 16);
      gll16(Wb + (size_t)(n0 + row) * 768 + kt * 64 + sl * 8, (char*)Bs + seg * 16);
    }
    __syncthreads();
#pragma unroll
    for (int kh = 0; kh < 2; ++kh) {
      bf16x8 af[4], bfr[4];
#pragma unroll
      for (int t = 0; t < 4; ++t) {
        int ra = wm + t * 16 + lr;
        af[t] = *(const bf16x8*)((const char*)As + ra * 128 +
                                 ((kh * 64 + lg * 16) ^ ((ra & 7) << 4)));
        int rb = wn + t * 16 + lr;
        bfr[t] = *(const bf16x8*)((const char*)Bs + rb * 128 +
                                  ((kh * 64 + lg * 16) ^ ((rb & 7) << 4)));
      }
#pragma unroll
      for (int mi = 0; mi < 4; ++mi)
#pragma unroll
        for (int ni = 0; ni < 4; ++ni)
          acc[mi][ni] = __builtin_amdgcn_mfma_f32_16x16x32_bf16(
              af[mi], bfr[ni], acc[mi][ni], 0, 0, 0);
    }
  }
  // epilogue: +b_in, scale q, scatter to [B,H,L,64] bf16
  const int sec = blockIdx.y / 6;  // 0=q,1=k,2=v
  u16* dst = sec == 0 ? gQ : (sec == 1 ? gK : gV);
  const float scale = sec == 0 ? 0.125f : 1.0f;
#pragma unroll
  for (int ni = 0; ni < 4; ++ni) {
    int e = n0 + wn + ni * 16 + lr;  // 0..2303
    float bias = b_in[e];
    int es = e - sec * 768;
    int h = es >> 6, d = es & 63;
#pragma unroll
    for (int mi = 0; mi < 4; ++mi) {
#pragma unroll
      for (int j = 0; j < 4; ++j) {
        int m = m0 + wm + mi * 16 + lg * 4 + j;
        int bb = m >> 10, lq = m & 1023;
        float vv = (acc[mi][ni][j] + bias) * scale;
        dst[(size_t)((bb * 12 + h) * 1024 + lq) * 64 + d] = f2bf(vv);
      }
    }
  }
}

// ---------------- V transpose: [B,H,L,64] -> [B,H,64,L] ---------------------
__global__ __launch_bounds__(256) void k_transpose(const u16* __restrict__ V,
                                                   u16* __restrict__ Vt) {
  __shared__ u16 t[64][66];
  const int tid = threadIdx.x;
  const int bh = blockIdx.x >> 4;
  const int kv0 = (blockIdx.x & 15) * 64;
  {
    int r = tid >> 2, c0 = (tid & 3) * 16;
    const u16* src = V + (size_t)(bh * 1024 + kv0 + r) * 64 + c0;
#pragma unroll
    for (int p = 0; p < 2; ++p) {
      u16x8 x = *(const u16x8*)(src + p * 8);
#pragma unroll
      for (int e = 0; e < 8; ++e) t[r][c0 + p * 8 + e] = x[e];
    }
  }
  __syncthreads();
  {
    int d = tid >> 2, k0 = (tid & 3) * 16;
    u16* dst = Vt + (size_t)(bh * 64 + d) * 1024 + kv0 + k0;
#pragma unroll
    for (int p = 0; p < 2; ++p) {
      u16x8 o;
#pragma unroll
      for (int e = 0; e < 8; ++e) o[e] = t[k0 + p * 8 + e][d];
      *(u16x8*)(dst + p * 8) = o;
    }
  }
}

// ---------------- fused flash attention (counted-vmcnt, depth-2 bias) -------
// T4 applied for real: KV double-buffered (1 tile ahead, L2-resident, cheap),
// bias TRIPLE-buffered (2 tiles ahead). Per tile: issue KV(t+1) then Bi(t+2);
// tile-end `s_waitcnt vmcnt(4)` + raw s_barrier -> the newest bias stage stays
// IN FLIGHT ACROSS the barrier; every bias load gets 2 full tile-times of
// cover. Never vmcnt(0) in steady state. P-bounce is carved from the wave's
// own 4KB slice of Bi[cur3] (read-before-write in program order) -> LDS = 80KB
// exactly -> 2 blocks/CU.
__global__ __launch_bounds__(256) void k_attn(
    const u16* __restrict__ gQ, const u16* __restrict__ gK,
    const u16* __restrict__ gVt, const float* __restrict__ gBias,
    u16* __restrict__ gO) {
  __shared__ u16 Ks[2][64 * 64];   // 16 KB [kv][d] rows 128B, src pre-swizzled
  __shared__ u16 Vs[2][64 * 64];   // 16 KB [d][kv]
  __shared__ float Bi[3][64 * 64]; // 48 KB [q][kv] fp32, slot-swizzled
  const int tid = threadIdx.x;
  const int lane = tid & 63;
  const int w = tid >> 6;
  const int lr = lane & 15;
  const int lg = lane >> 4;
  // XCD-bijective swizzle: 768 = 8 XCDs x 96; the 16 q-blocks sharing one
  // (b,h)'s K/V land on one XCD -> K/V stay L2-resident.
  const int lb = (blockIdx.x & 7) * 96 + (blockIdx.x >> 3);
  const int bh = lb >> 4;
  const int q0 = (lb & 15) * 64;
  const int qr = q0 + w * 16;  // wave's q-row base; lane's q-row = qr + lr

#define STAGE_KV(buf, kv0)                                                     \
  do {                                                                         \
    _Pragma("unroll") for (int i_ = 0; i_ < 2; ++i_) {                         \
      int seg_ = i_ * 256 + tid;                                               \
      int row_ = seg_ >> 3;                                                    \
      int sl_ = (seg_ & 7) ^ (row_ & 7);                                       \
      gll16(gK + (size_t)(bh * 1024 + (kv0) + row_) * 64 + sl_ * 8,            \
            (char*)Ks[buf] + seg_ * 16);                                       \
      gll16(gVt + (size_t)(bh * 64 + row_) * 1024 + (kv0) + sl_ * 8,           \
            (char*)Vs[buf] + seg_ * 16);                                       \
    }                                                                          \
  } while (0)

#define STAGE_BI(buf, kv0)                                                     \
  do {                                                                         \
    _Pragma("unroll") for (int i_ = 0; i_ < 4; ++i_) {                         \
      int seg_ = i_ * 256 + tid;                                               \
      int qrow_ = seg_ >> 4;                                                   \
      int c_ = (seg_ & 15) ^ (qrow_ & 7);                                      \
      gll16(gBias + (size_t)(bh * 1024 + q0 + qrow_) * 1024 + (kv0) + c_ * 4,  \
            (char*)Bi[buf] + seg_ * 16);                                       \
    }                                                                          \
  } while (0)

  // Q as B-operand: rows q = qr+lr (pre-scaled by 1/8 in GEMM1)
  bf16x8 qa[2];
#pragma unroll
  for (int kh = 0; kh < 2; ++kh)
    qa[kh] = *(const bf16x8*)(gQ + (size_t)(bh * 1024 + qr + lr) * 64 + kh * 32 + lg * 8);

  f32x4 oacc[4];
#pragma unroll
  for (int dt = 0; dt < 4; ++dt) oacc[dt] = (f32x4){0.f, 0.f, 0.f, 0.f};
  float mrow = -1e30f, lrow = 0.f;

  const int swz = (lr & 7) << 4;

  // prologue: KV(0), Bi(0), Bi(1); wait leaves Bi(1)'s 4 instr in flight
  STAGE_KV(0, 0);
  STAGE_BI(0, 0);
  STAGE_BI(1, 64);
  asm volatile("s_waitcnt vmcnt(4)" ::: "memory");
  __builtin_amdgcn_s_barrier();

  for (int t = 0; t < 16; ++t) {
    const int cur2 = t & 1;
    const int cur3 = t % 3;
    if (t < 15) STAGE_KV(cur2 ^ 1, (t + 1) * 64);                 // 4 instr
    if (t < 14) STAGE_BI((t + 2) % 3, (t + 2) * 64);              // 4 instr

    // S^T = K Q^T : s[ni][j] = S[kv = ni*16+lg*4+j][q = qr+lr]
    f32x4 s[4];
#pragma unroll
    for (int ni = 0; ni < 4; ++ni) s[ni] = (f32x4){0.f, 0.f, 0.f, 0.f};
    __builtin_amdgcn_s_setprio(1);
#pragma unroll
    for (int kh = 0; kh < 2; ++kh)
#pragma unroll
      for (int ni = 0; ni < 4; ++ni) {
        int rk = ni * 16 + lr;
        bf16x8 kb = *(const bf16x8*)((const char*)Ks[cur2] + rk * 128 +
                                     ((kh * 64 + lg * 16) ^ ((rk & 7) << 4)));
        s[ni] = __builtin_amdgcn_mfma_f32_16x16x32_bf16(kb, qa[kh], s[ni], 0, 0, 0);
      }
    __builtin_amdgcn_s_setprio(0);

    // + bias from LDS: lane needs bias[q=qr+lr][kv0 + ni*16 + lg*4 + j]
#pragma unroll
    for (int ni = 0; ni < 4; ++ni) {
      f32x4 bv = *(const f32x4*)((const char*)Bi[cur3] + (w * 16 + lr) * 256 +
                                 (((ni * 4 + lg) ^ (lr & 7)) << 4));
      s[ni] += bv;
    }

    // lane-local online softmax for q-row (qr+lr)
    float mx0 = fmaxf(fmaxf(s[0][0], s[0][1]), fmaxf(s[0][2], s[0][3]));
    float mx1 = fmaxf(fmaxf(s[1][0], s[1][1]), fmaxf(s[1][2], s[1][3]));
    float mx2 = fmaxf(fmaxf(s[2][0], s[2][1]), fmaxf(s[2][2], s[2][3]));
    float mx3 = fmaxf(fmaxf(s[3][0], s[3][1]), fmaxf(s[3][2], s[3][3]));
    float vmax = fmaxf(fmaxf(mx0, mx1), fmaxf(mx2, mx3));
    vmax = fmaxf(vmax, __shfl_xor(vmax, 16));
    vmax = fmaxf(vmax, __shfl_xor(vmax, 32));
    float mnew = fmaxf(mrow, vmax);
    float al = __expf(mrow - mnew);
    mrow = mnew;
#pragma unroll
    for (int ni = 0; ni < 4; ++ni)
#pragma unroll
      for (int j = 0; j < 4; ++j) s[ni][j] = __expf(s[ni][j] - mnew);
    float r0 = (s[0][0] + s[0][1]) + (s[0][2] + s[0][3]);
    float r1 = (s[1][0] + s[1][1]) + (s[1][2] + s[1][3]);
    float r2 = (s[2][0] + s[2][1]) + (s[2][2] + s[2][3]);
    float r3 = (s[3][0] + s[3][1]) + (s[3][2] + s[3][3]);
    float rs = (r0 + r1) + (r2 + r3);
    rs += __shfl_xor(rs, 16);
    rs += __shfl_xor(rs, 32);
    lrow = lrow * al + rs;

    // broadcast al from lane (lr = q) to the oacc owners (q = lg*4+j)
    f32x4 av;
#pragma unroll
    for (int j = 0; j < 4; ++j) av[j] = __shfl(al, (lane & 48) | (lg * 4 + j));
#pragma unroll
    for (int dt = 0; dt < 4; ++dt) oacc[dt] *= av;

    // P pack -> wave-private 4KB slice of Bi[cur3] (already consumed above),
    // swizzled b64 writes; read back as A-fragment for PV.
    char* plw = (char*)Bi[cur3] + w * 4096;
#pragma unroll
    for (int ni = 0; ni < 4; ++ni) {
      uint32_t w0 = (uint32_t)f2bf(s[ni][0]) | ((uint32_t)f2bf(s[ni][1]) << 16);
      uint32_t w1 = (uint32_t)f2bf(s[ni][2]) | ((uint32_t)f2bf(s[ni][3]) << 16);
      u32x2 pv = {w0, w1};
      *(u32x2*)(plw + lr * 128 + ((ni * 32 + lg * 8) ^ swz)) = pv;
    }
    __builtin_amdgcn_s_setprio(1);
#pragma unroll
    for (int kh = 0; kh < 2; ++kh) {
      bf16x8 pa = *(const bf16x8*)(plw + lr * 128 + ((kh * 64 + lg * 16) ^ swz));
#pragma unroll
      for (int dt = 0; dt < 4; ++dt) {
        int rv = dt * 16 + lr;
        bf16x8 vb = *(const bf16x8*)((const char*)Vs[cur2] + rv * 128 +
                                     ((kh * 64 + lg * 16) ^ ((rv & 7) << 4)));
        oacc[dt] = __builtin_amdgcn_mfma_f32_16x16x32_bf16(pa, vb, oacc[dt], 0, 0, 0);
      }
    }
    __builtin_amdgcn_s_setprio(0);

    // tile-end: publish KV(t+1) + Bi(t+1); keep Bi(t+2)'s 4 loads in flight
    if (t <= 13) {
      asm volatile("s_waitcnt vmcnt(4)" ::: "memory");
      __builtin_amdgcn_s_barrier();
    } else if (t == 14) {
      asm volatile("s_waitcnt vmcnt(0)" ::: "memory");
      __builtin_amdgcn_s_barrier();
    }
  }

  // normalize + store O bf16 [B,L,D]; inv broadcast like al
  float inv = 1.0f / lrow;
  f32x4 iv;
#pragma unroll
  for (int j = 0; j < 4; ++j) iv[j] = __shfl(inv, (lane & 48) | (lg * 4 + j));
  const int bg = bh / 12, h = bh % 12;
#pragma unroll
  for (int j = 0; j < 4; ++j) {
    int row = qr + lg * 4 + j;
#pragma unroll
    for (int dt = 0; dt < 4; ++dt) {
      gO[(size_t)(bg * 1024 + row) * 768 + h * 64 + dt * 16 + lr] =
          f2bf(oacc[dt][j] * iv[j]);
    }
  }
#undef STAGE_KV
#undef STAGE_BI
}

// ---------------- GEMM2: out = O @ w_out^T + b_out (fp32 out), 64x64 tiles --
__global__ __launch_bounds__(256) void k_gemm_out(
    const u16* __restrict__ Ob, const u16* __restrict__ Wb,
    const float* __restrict__ b_out, float* __restrict__ out) {
  __shared__ u16 As[64 * 64];
  __shared__ u16 Bs[64 * 64];
  const int tid = threadIdx.x;
  const int lane = tid & 63;
  const int w = tid >> 6;
  const int wm = (w >> 1) * 32;
  const int wn = (w & 1) * 32;
  const int lr = lane & 15;
  const int lg = lane >> 4;
  const int m0 = blockIdx.x * 64;
  const int n0 = blockIdx.y * 64;

  f32x4 acc[2][2];
#pragma unroll
  for (int i = 0; i < 2; ++i)
#pragma unroll
    for (int j = 0; j < 2; ++j) acc[i][j] = (f32x4){0.f, 0.f, 0.f, 0.f};

  for (int kt = 0; kt < 12; ++kt) {
    __syncthreads();
#pragma unroll
    for (int i = 0; i < 2; ++i) {
      int seg = i * 256 + tid;
      int row = seg >> 3;
      int sl = (seg & 7) ^ (row & 7);
      gll16(Ob + (size_t)(m0 + row) * 768 + kt * 64 + sl * 8, (char*)As + seg * 16);
      gll16(Wb + (size_t)(n0 + row) * 768 + kt * 64 + sl * 8, (char*)Bs + seg * 16);
    }
    __syncthreads();
#pragma unroll
    for (int kh = 0; kh < 2; ++kh) {
      bf16x8 af[2], bfr[2];
#pragma unroll
      for (int t = 0; t < 2; ++t) {
        int ra = wm + t * 16 + lr;
        af[t] = *(const bf16x8*)((const char*)As + ra * 128 +
                                 ((kh * 64 + lg * 16) ^ ((ra & 7) << 4)));
        int rb = wn + t * 16 + lr;
        bfr[t] = *(const bf16x8*)((const char*)Bs + rb * 128 +
                                  ((kh * 64 + lg * 16) ^ ((rb & 7) << 4)));
      }
#pragma unroll
      for (int mi = 0; mi < 2; ++mi)
#pragma unroll
        for (int ni = 0; ni < 2; ++ni)
          acc[mi][ni] = __builtin_amdgcn_mfma_f32_16x16x32_bf16(
              af[mi], bfr[ni], acc[mi][ni], 0, 0, 0);
    }
  }
#pragma unroll
  for (int ni = 0; ni < 2; ++ni) {
    int n = n0 + wn + ni * 16 + lr;
    float bias = b_out[n];
#pragma unroll
    for (int mi = 0; mi < 2; ++mi) {
#pragma unroll
      for (int j = 0; j < 4; ++j) {
        int m = m0 + wm + mi * 16 + lg * 4 + j;
        out[(size_t)m * 768 + n] = acc[mi][ni][j] + bias;
      }
    }
  }
}

extern "C" void kernel_launch(void* const* d_in, const int* in_sizes, int n_in,
                              void* d_out, int out_size, void* d_ws, size_t ws_size,
                              hipStream_t stream) {
  const float* x = (const float*)d_in[0];
  const float* attn_bias = (const float*)d_in[1];
  const float* w_in = (const float*)d_in[2];
  const float* b_in = (const float*)d_in[3];
  const float* w_out = (const float*)d_in[4];
  const float* b_out = (const float*)d_in[5];
  float* out = (float*)d_out;

  char* ws = (char*)d_ws;
  size_t off = 0;
  u16* xb = (u16*)(ws + off);  off += (size_t)M_ * D_ * 2;
  u16* wib = (u16*)(ws + off); off += (size_t)N3_ * D_ * 2;
  u16* wob = (u16*)(ws + off); off += (size_t)D_ * D_ * 2;
  u16* q = (u16*)(ws + off);   off += (size_t)48 * 1024 * 64 * 2;
  u16* k = (u16*)(ws + off);   off += (size_t)48 * 1024 * 64 * 2;
  u16* v = (u16*)(ws + off);   off += (size_t)48 * 1024 * 64 * 2;
  u16* vt = (u16*)(ws + off);  off += (size_t)48 * 1024 * 64 * 2;
  u16* ob = (u16*)(ws + off);  off += (size_t)M_ * D_ * 2;

  const int na4 = (M_ * D_) / 4;
  const int nb4 = (N3_ * D_) / 4;
  const int nc4 = (D_ * D_) / 4;
  k_cvt3<<<(na4 + nb4 + nc4 + 255) / 256, 256, 0, stream>>>(
      x, xb, na4, w_in, wib, nb4, w_out, wob, nc4);
  k_gemm_qkv<<<dim3(32, 18), 256, 0, stream>>>(xb, wib, b_in, q, k, v);
  k_transpose<<<768, 256, 0, stream>>>(v, vt);
  k_attn<<<768, 256, 0, stream>>>(q, k, vt, attn_bias, ob);
  k_gemm_out<<<dim3(64, 12), 256, 0, stream>>>(ob, wob, b_out, out);
}

// Round 10
// 115.780 us; speedup vs baseline: 1.3793x; 1.0691x over previous
//
#include <hip/hip_runtime.h>
#include <hip/hip_bf16.h>
#include <stdint.h>

// Problem constants
#define B_ 4
#define L_ 1024
#define D_ 768
#define H_ 12
#define HD_ 64
#define M_ 4096     // B*L
#define N3_ 2304    // 3*D

typedef float f32x4 __attribute__((ext_vector_type(4)));
typedef float f32x4v __attribute__((ext_vector_type(4)));
typedef short bf16x8 __attribute__((ext_vector_type(8)));
typedef unsigned short u16;
typedef u16 u16x8 __attribute__((ext_vector_type(8)));
typedef u16 u16x4 __attribute__((ext_vector_type(4)));
typedef uint32_t u32x2 __attribute__((ext_vector_type(2)));

#define AS3 __attribute__((address_space(3)))
#define AS1 __attribute__((address_space(1)))

__device__ __forceinline__ void gll16(const void* g, void* l) {
  __builtin_amdgcn_global_load_lds((const AS1 void*)g, (AS3 void*)l, 16, 0, 0);
}

// fp32 -> bf16 round-to-nearest-even (finite data)
__device__ __forceinline__ u16 f2bf(float f) {
  uint32_t u = __builtin_bit_cast(uint32_t, f);
  u += 0x7fffu + ((u >> 16) & 1u);
  return (u16)(u >> 16);
}

// ---------------- fused conversion kernel (3 tensors, fp32 -> bf16) ---------
__global__ void k_cvt3(const float* __restrict__ a, u16* __restrict__ ao, int na4,
                       const float* __restrict__ b, u16* __restrict__ bo, int nb4,
                       const float* __restrict__ c, u16* __restrict__ co, int nc4) {
  int i = blockIdx.x * 256 + threadIdx.x;
  const float* src;
  u16* dst;
  if (i < na4) {
    src = a; dst = ao;
  } else if (i < na4 + nb4) {
    src = b; dst = bo; i -= na4;
  } else if (i < na4 + nb4 + nc4) {
    src = c; dst = co; i -= na4 + nb4;
  } else {
    return;
  }
  f32x4v v = ((const f32x4v*)src)[i];
  u16x4 o;
  o.x = f2bf(v.x); o.y = f2bf(v.y); o.z = f2bf(v.z); o.w = f2bf(v.w);
  ((u16x4*)dst)[i] = o;
}

// ---------------- GEMM1: qkv = x @ w_in^T + b_in -> Q,K,V bf16 [B,H,L,64] ----
__global__ __launch_bounds__(256) void k_gemm_qkv(
    const u16* __restrict__ Xb, const u16* __restrict__ Wb,
    const float* __restrict__ b_in,
    u16* __restrict__ gQ, u16* __restrict__ gK, u16* __restrict__ gV) {
  __shared__ u16 As[128 * 64];
  __shared__ u16 Bs[128 * 64];
  const int tid = threadIdx.x;
  const int lane = tid & 63;
  const int w = tid >> 6;
  const int wm = (w >> 1) * 64;
  const int wn = (w & 1) * 64;
  const int lr = lane & 15;
  const int lg = lane >> 4;
  const int m0 = blockIdx.x * 128;
  const int n0 = blockIdx.y * 128;

  f32x4 acc[4][4];
#pragma unroll
  for (int i = 0; i < 4; ++i)
#pragma unroll
    for (int j = 0; j < 4; ++j) acc[i][j] = (f32x4){0.f, 0.f, 0.f, 0.f};

  for (int kt = 0; kt < 12; ++kt) {
    __syncthreads();
#pragma unroll
    for (int i = 0; i < 4; ++i) {
      int seg = i * 256 + tid;
      int row = seg >> 3;
      int sl = (seg & 7) ^ (row & 7);
      gll16(Xb + (size_t)(m0 + row) * 768 + kt * 64 + sl * 8, (char*)As + seg * 16);
      gll16(Wb + (size_t)(n0 + row) * 768 + kt * 64 + sl * 8, (char*)Bs + seg * 16);
    }
    __syncthreads();
#pragma unroll
    for (int kh = 0; kh < 2; ++kh) {
      bf16x8 af[4], bfr[4];
#pragma unroll
      for (int t = 0; t < 4; ++t) {
        int ra = wm + t * 16 + lr;
        af[t] = *(const bf16x8*)((const char*)As + ra * 128 +
                                 ((kh * 64 + lg * 16) ^ ((ra & 7) << 4)));
        int rb = wn + t * 16 + lr;
        bfr[t] = *(const bf16x8*)((const char*)Bs + rb * 128 +
                                  ((kh * 64 + lg * 16) ^ ((rb & 7) << 4)));
      }
#pragma unroll
      for (int mi = 0; mi < 4; ++mi)
#pragma unroll
        for (int ni = 0; ni < 4; ++ni)
          acc[mi][ni] = __builtin_amdgcn_mfma_f32_16x16x32_bf16(
              af[mi], bfr[ni], acc[mi][ni], 0, 0, 0);
    }
  }
  // epilogue: +b_in, scale q, scatter to [B,H,L,64] bf16
  const int sec = blockIdx.y / 6;  // 0=q,1=k,2=v
  u16* dst = sec == 0 ? gQ : (sec == 1 ? gK : gV);
  const float scale = sec == 0 ? 0.125f : 1.0f;
#pragma unroll
  for (int ni = 0; ni < 4; ++ni) {
    int e = n0 + wn + ni * 16 + lr;  // 0..2303
    float bias = b_in[e];
    int es = e - sec * 768;
    int h = es >> 6, d = es & 63;
#pragma unroll
    for (int mi = 0; mi < 4; ++mi) {
#pragma unroll
      for (int j = 0; j < 4; ++j) {
        int m = m0 + wm + mi * 16 + lg * 4 + j;
        int bb = m >> 10, lq = m & 1023;
        float vv = (acc[mi][ni][j] + bias) * scale;
        dst[(size_t)((bb * 12 + h) * 1024 + lq) * 64 + d] = f2bf(vv);
      }
    }
  }
}

// ---------------- V transpose: [B,H,L,64] -> [B,H,64,L] ---------------------
__global__ __launch_bounds__(256) void k_transpose(const u16* __restrict__ V,
                                                   u16* __restrict__ Vt) {
  __shared__ u16 t[64][66];
  const int tid = threadIdx.x;
  const int bh = blockIdx.x >> 4;
  const int kv0 = (blockIdx.x & 15) * 64;
  {
    int r = tid >> 2, c0 = (tid & 3) * 16;
    const u16* src = V + (size_t)(bh * 1024 + kv0 + r) * 64 + c0;
#pragma unroll
    for (int p = 0; p < 2; ++p) {
      u16x8 x = *(const u16x8*)(src + p * 8);
#pragma unroll
      for (int e = 0; e < 8; ++e) t[r][c0 + p * 8 + e] = x[e];
    }
  }
  __syncthreads();
  {
    int d = tid >> 2, k0 = (tid & 3) * 16;
    u16* dst = Vt + (size_t)(bh * 64 + d) * 1024 + kv0 + k0;
#pragma unroll
    for (int p = 0; p < 2; ++p) {
      u16x8 o;
#pragma unroll
      for (int e = 0; e < 8; ++e) o[e] = t[k0 + p * 8 + e][d];
      *(u16x8*)(dst + p * 8) = o;
    }
  }
}

// ---------------- fused flash attention (q-tile 128: halved K/V staging) ----
// Each block: 128 q-rows; each wave owns TWO 16-row subtiles (p=0: q0+w*16,
// p=1: q0+64+w*16). K/V staged to LDS once per tile serve both subtiles
// (8 ds_reads -> 16 MFMAs), cutting K/V re-staging from 16x to 8x per bh
// (-96 MB of the 384 MB total staged traffic -> ~25% less at the measured
// ~4.9 TB/s service ceiling). Bias: per-lane register loads (R1-style),
// issued right after consumption, drained by tile-end barrier.
__global__ __launch_bounds__(256) void k_attn(
    const u16* __restrict__ gQ, const u16* __restrict__ gK,
    const u16* __restrict__ gVt, const float* __restrict__ gBias,
    u16* __restrict__ gO) {
  __shared__ u16 Ks[2][64 * 64];  // 16 KB [kv][d] rows 128B, src pre-swizzled
  __shared__ u16 Vs[2][64 * 64];  // 16 KB [d][kv]
  __shared__ f32x4 PlV[4][256];   // 16 KB: per-wave 4KB (2KB per subtile)
  const int tid = threadIdx.x;
  const int lane = tid & 63;
  const int w = tid >> 6;
  const int lr = lane & 15;
  const int lg = lane >> 4;
  // XCD-bijective swizzle: 384 = 8 XCDs x 48; the 8 q-blocks sharing one
  // (b,h)'s K/V land on one XCD -> K/V stay L2-resident.
  const int lb = (blockIdx.x & 7) * 48 + (blockIdx.x >> 3);
  const int bh = lb >> 3;
  const int q0 = (lb & 7) * 128;
  const int qr0 = q0 + w * 16;       // subtile 0 base
  const int qr1 = q0 + 64 + w * 16;  // subtile 1 base

#define STAGE_KV(buf, kv0)                                                     \
  do {                                                                         \
    _Pragma("unroll") for (int i_ = 0; i_ < 2; ++i_) {                         \
      int seg_ = i_ * 256 + tid;                                               \
      int row_ = seg_ >> 3;                                                    \
      int sl_ = (seg_ & 7) ^ (row_ & 7);                                       \
      gll16(gK + (size_t)(bh * 1024 + (kv0) + row_) * 64 + sl_ * 8,            \
            (char*)Ks[buf] + seg_ * 16);                                       \
      gll16(gVt + (size_t)(bh * 64 + row_) * 1024 + (kv0) + sl_ * 8,           \
            (char*)Vs[buf] + seg_ * 16);                                       \
    }                                                                          \
  } while (0)

  const float* bline0 = gBias + (size_t)(bh * 1024 + qr0 + lr) * 1024;
  const float* bline1 = gBias + (size_t)(bh * 1024 + qr1 + lr) * 1024;

  // Q as B-operand (pre-scaled by 1/8 in GEMM1)
  bf16x8 qa[2][2];
#pragma unroll
  for (int kh = 0; kh < 2; ++kh) {
    qa[0][kh] = *(const bf16x8*)(gQ + (size_t)(bh * 1024 + qr0 + lr) * 64 + kh * 32 + lg * 8);
    qa[1][kh] = *(const bf16x8*)(gQ + (size_t)(bh * 1024 + qr1 + lr) * 64 + kh * 32 + lg * 8);
  }

  f32x4 oacc[2][4];
#pragma unroll
  for (int p = 0; p < 2; ++p)
#pragma unroll
    for (int dt = 0; dt < 4; ++dt) oacc[p][dt] = (f32x4){0.f, 0.f, 0.f, 0.f};
  float mrow[2] = {-1e30f, -1e30f}, lrow[2] = {0.f, 0.f};

  char* plw = (char*)PlV[w];
  const int swz = (lr & 7) << 4;

  // prologue: stage KV(0); load bias tile 0 for both subtiles
  STAGE_KV(0, 0);
  f32x4 bcur[2][4];
#pragma unroll
  for (int ni = 0; ni < 4; ++ni) {
    bcur[0][ni] = *(const f32x4*)(bline0 + ni * 16 + lg * 4);
    bcur[1][ni] = *(const f32x4*)(bline1 + ni * 16 + lg * 4);
  }
  __syncthreads();

  for (int t = 0; t < 16; ++t) {
    const int cur = t & 1;
    const int kv0 = t * 64;
    if (t < 15) STAGE_KV(cur ^ 1, kv0 + 64);  // in flight across whole tile

    // S^T = K Q^T for both subtiles; kb shared (8 ds_reads -> 16 MFMAs)
    f32x4 s[2][4];
#pragma unroll
    for (int p = 0; p < 2; ++p)
#pragma unroll
      for (int ni = 0; ni < 4; ++ni) s[p][ni] = (f32x4){0.f, 0.f, 0.f, 0.f};
    __builtin_amdgcn_s_setprio(1);
#pragma unroll
    for (int kh = 0; kh < 2; ++kh)
#pragma unroll
      for (int ni = 0; ni < 4; ++ni) {
        int rk = ni * 16 + lr;
        bf16x8 kb = *(const bf16x8*)((const char*)Ks[cur] + rk * 128 +
                                     ((kh * 64 + lg * 16) ^ ((rk & 7) << 4)));
        s[0][ni] = __builtin_amdgcn_mfma_f32_16x16x32_bf16(kb, qa[0][kh], s[0][ni], 0, 0, 0);
        s[1][ni] = __builtin_amdgcn_mfma_f32_16x16x32_bf16(kb, qa[1][kh], s[1][ni], 0, 0, 0);
      }
    __builtin_amdgcn_s_setprio(0);

    // + bias, then issue next tile's bias (drained by tile-end barrier)
#pragma unroll
    for (int ni = 0; ni < 4; ++ni) {
      s[0][ni] += bcur[0][ni];
      s[1][ni] += bcur[1][ni];
    }
    if (t < 15) {
#pragma unroll
      for (int ni = 0; ni < 4; ++ni) {
        bcur[0][ni] = *(const f32x4*)(bline0 + kv0 + 64 + ni * 16 + lg * 4);
        bcur[1][ni] = *(const f32x4*)(bline1 + kv0 + 64 + ni * 16 + lg * 4);
      }
    }

    // lane-local online softmax per subtile (independent chains -> ILP)
#pragma unroll
    for (int p = 0; p < 2; ++p) {
      float mx0 = fmaxf(fmaxf(s[p][0][0], s[p][0][1]), fmaxf(s[p][0][2], s[p][0][3]));
      float mx1 = fmaxf(fmaxf(s[p][1][0], s[p][1][1]), fmaxf(s[p][1][2], s[p][1][3]));
      float mx2 = fmaxf(fmaxf(s[p][2][0], s[p][2][1]), fmaxf(s[p][2][2], s[p][2][3]));
      float mx3 = fmaxf(fmaxf(s[p][3][0], s[p][3][1]), fmaxf(s[p][3][2], s[p][3][3]));
      float vmax = fmaxf(fmaxf(mx0, mx1), fmaxf(mx2, mx3));
      vmax = fmaxf(vmax, __shfl_xor(vmax, 16));
      vmax = fmaxf(vmax, __shfl_xor(vmax, 32));
      float mnew = fmaxf(mrow[p], vmax);
      float al = __expf(mrow[p] - mnew);
      mrow[p] = mnew;
#pragma unroll
      for (int ni = 0; ni < 4; ++ni)
#pragma unroll
        for (int j = 0; j < 4; ++j) s[p][ni][j] = __expf(s[p][ni][j] - mnew);
      float r0 = (s[p][0][0] + s[p][0][1]) + (s[p][0][2] + s[p][0][3]);
      float r1 = (s[p][1][0] + s[p][1][1]) + (s[p][1][2] + s[p][1][3]);
      float r2 = (s[p][2][0] + s[p][2][1]) + (s[p][2][2] + s[p][2][3]);
      float r3 = (s[p][3][0] + s[p][3][1]) + (s[p][3][2] + s[p][3][3]);
      float rs = (r0 + r1) + (r2 + r3);
      rs += __shfl_xor(rs, 16);
      rs += __shfl_xor(rs, 32);
      lrow[p] = lrow[p] * al + rs;
      f32x4 av;
#pragma unroll
      for (int j = 0; j < 4; ++j) av[j] = __shfl(al, (lane & 48) | (lg * 4 + j));
#pragma unroll
      for (int dt = 0; dt < 4; ++dt) oacc[p][dt] *= av;
    }

    // P pack both subtiles -> per-wave LDS slices, then PV (vb shared)
#pragma unroll
    for (int p = 0; p < 2; ++p) {
      char* pl = plw + p * 2048;
#pragma unroll
      for (int ni = 0; ni < 4; ++ni) {
        uint32_t w0 = (uint32_t)f2bf(s[p][ni][0]) | ((uint32_t)f2bf(s[p][ni][1]) << 16);
        uint32_t w1 = (uint32_t)f2bf(s[p][ni][2]) | ((uint32_t)f2bf(s[p][ni][3]) << 16);
        u32x2 pv = {w0, w1};
        *(u32x2*)(pl + lr * 128 + ((ni * 32 + lg * 8) ^ swz)) = pv;
      }
    }
    __builtin_amdgcn_s_setprio(1);
#pragma unroll
    for (int kh = 0; kh < 2; ++kh) {
      bf16x8 pa0 = *(const bf16x8*)(plw + lr * 128 + ((kh * 64 + lg * 16) ^ swz));
      bf16x8 pa1 = *(const bf16x8*)(plw + 2048 + lr * 128 + ((kh * 64 + lg * 16) ^ swz));
#pragma unroll
      for (int dt = 0; dt < 4; ++dt) {
        int rv = dt * 16 + lr;
        bf16x8 vb = *(const bf16x8*)((const char*)Vs[cur] + rv * 128 +
                                     ((kh * 64 + lg * 16) ^ ((rv & 7) << 4)));
        oacc[0][dt] = __builtin_amdgcn_mfma_f32_16x16x32_bf16(pa0, vb, oacc[0][dt], 0, 0, 0);
        oacc[1][dt] = __builtin_amdgcn_mfma_f32_16x16x32_bf16(pa1, vb, oacc[1][dt], 0, 0, 0);
      }
    }
    __builtin_amdgcn_s_setprio(0);

    __syncthreads();  // drains KV(t+1) + bias loads; publishes buf cur^1
  }

  // normalize + store O bf16 [B,L,D]
  const int bg = bh / 12, h = bh % 12;
#pragma unroll
  for (int p = 0; p < 2; ++p) {
    float inv = 1.0f / lrow[p];
    f32x4 iv;
#pragma unroll
    for (int j = 0; j < 4; ++j) iv[j] = __shfl(inv, (lane & 48) | (lg * 4 + j));
    const int qrp = p == 0 ? qr0 : qr1;
#pragma unroll
    for (int j = 0; j < 4; ++j) {
      int row = qrp + lg * 4 + j;
#pragma unroll
      for (int dt = 0; dt < 4; ++dt) {
        gO[(size_t)(bg * 1024 + row) * 768 + h * 64 + dt * 16 + lr] =
            f2bf(oacc[p][dt][j] * iv[j]);
      }
    }
  }
#undef STAGE_KV
}

// ---------------- GEMM2: out = O @ w_out^T + b_out (fp32 out), 64x64 tiles --
__global__ __launch_bounds__(256) void k_gemm_out(
    const u16* __restrict__ Ob, const u16* __restrict__ Wb,
    const float* __restrict__ b_out, float* __restrict__ out) {
  __shared__ u16 As[64 * 64];
  __shared__ u16 Bs[64 * 64];
  const int tid = threadIdx.x;
  const int lane = tid & 63;
  const int w = tid >> 6;
  const int wm = (w >> 1) * 32;
  const int wn = (w & 1) * 32;
  const int lr = lane & 15;
  const int lg = lane >> 4;
  const int m0 = blockIdx.x * 64;
  const int n0 = blockIdx.y * 64;

  f32x4 acc[2][2];
#pragma unroll
  for (int i = 0; i < 2; ++i)
#pragma unroll
    for (int j = 0; j < 2; ++j) acc[i][j] = (f32x4){0.f, 0.f, 0.f, 0.f};

  for (int kt = 0; kt < 12; ++kt) {
    __syncthreads();
#pragma unroll
    for (int i = 0; i < 2; ++i) {
      int seg = i * 256 + tid;
      int row = seg >> 3;
      int sl = (seg & 7) ^ (row & 7);
      gll16(Ob + (size_t)(m0 + row) * 768 + kt * 64 + sl * 8, (char*)As + seg * 16);
      gll16(Wb + (size_t)(n0 + row) * 768 + kt * 64 + sl * 8, (char*)Bs + seg * 16);
    }
    __syncthreads();
#pragma unroll
    for (int kh = 0; kh < 2; ++kh) {
      bf16x8 af[2], bfr[2];
#pragma unroll
      for (int t = 0; t < 2; ++t) {
        int ra = wm + t * 16 + lr;
        af[t] = *(const bf16x8*)((const char*)As + ra * 128 +
                                 ((kh * 64 + lg * 16) ^ ((ra & 7) << 4)));
        int rb = wn + t * 16 + lr;
        bfr[t] = *(const bf16x8*)((const char*)Bs + rb * 128 +
                                  ((kh * 64 + lg * 16) ^ ((rb & 7) << 4)));
      }
#pragma unroll
      for (int mi = 0; mi < 2; ++mi)
#pragma unroll
        for (int ni = 0; ni < 2; ++ni)
          acc[mi][ni] = __builtin_amdgcn_mfma_f32_16x16x32_bf16(
              af[mi], bfr[ni], acc[mi][ni], 0, 0, 0);
    }
  }
#pragma unroll
  for (int ni = 0; ni < 2; ++ni) {
    int n = n0 + wn + ni * 16 + lr;
    float bias = b_out[n];
#pragma unroll
    for (int mi = 0; mi < 2; ++mi) {
#pragma unroll
      for (int j = 0; j < 4; ++j) {
        int m = m0 + wm + mi * 16 + lg * 4 + j;
        out[(size_t)m * 768 + n] = acc[mi][ni][j] + bias;
      }
    }
  }
}

extern "C" void kernel_launch(void* const* d_in, const int* in_sizes, int n_in,
                              void* d_out, int out_size, void* d_ws, size_t ws_size,
                              hipStream_t stream) {
  const float* x = (const float*)d_in[0];
  const float* attn_bias = (const float*)d_in[1];
  const float* w_in = (const float*)d_in[2];
  const float* b_in = (const float*)d_in[3];
  const float* w_out = (const float*)d_in[4];
  const float* b_out = (const float*)d_in[5];
  float* out = (float*)d_out;

  char* ws = (char*)d_ws;
  size_t off = 0;
  u16* xb = (u16*)(ws + off);  off += (size_t)M_ * D_ * 2;
  u16* wib = (u16*)(ws + off); off += (size_t)N3_ * D_ * 2;
  u16* wob = (u16*)(ws + off); off += (size_t)D_ * D_ * 2;
  u16* q = (u16*)(ws + off);   off += (size_t)48 * 1024 * 64 * 2;
  u16* k = (u16*)(ws + off);   off += (size_t)48 * 1024 * 64 * 2;
  u16* v = (u16*)(ws + off);   off += (size_t)48 * 1024 * 64 * 2;
  u16* vt = (u16*)(ws + off);  off += (size_t)48 * 1024 * 64 * 2;
  u16* ob = (u16*)(ws + off);  off += (size_t)M_ * D_ * 2;

  const int na4 = (M_ * D_) / 4;
  const int nb4 = (N3_ * D_) / 4;
  const int nc4 = (D_ * D_) / 4;
  k_cvt3<<<(na4 + nb4 + nc4 + 255) / 256, 256, 0, stream>>>(
      x, xb, na4, w_in, wib, nb4, w_out, wob, nc4);
  k_gemm_qkv<<<dim3(32, 18), 256, 0, stream>>>(xb, wib, b_in, q, k, v);
  k_transpose<<<768, 256, 0, stream>>>(v, vt);
  k_attn<<<384, 256, 0, stream>>>(q, k, vt, attn_bias, ob);
  k_gemm_out<<<dim3(64, 12), 256, 0, stream>>>(ob, wob, b_out, out);
}

// Round 11
// 114.328 us; speedup vs baseline: 1.3968x; 1.0127x over previous
//
#include <hip/hip_runtime.h>
#include <hip/hip_bf16.h>
#include <stdint.h>

// Problem constants
#define B_ 4
#define L_ 1024
#define D_ 768
#define H_ 12
#define HD_ 64
#define M_ 4096     // B*L
#define N3_ 2304    // 3*D

typedef float f32x4 __attribute__((ext_vector_type(4)));
typedef float f32x4v __attribute__((ext_vector_type(4)));
typedef short bf16x8 __attribute__((ext_vector_type(8)));
typedef unsigned short u16;
typedef u16 u16x8 __attribute__((ext_vector_type(8)));
typedef u16 u16x4 __attribute__((ext_vector_type(4)));
typedef uint32_t u32x2 __attribute__((ext_vector_type(2)));

#define AS3 __attribute__((address_space(3)))
#define AS1 __attribute__((address_space(1)))

__device__ __forceinline__ void gll16(const void* g, void* l) {
  __builtin_amdgcn_global_load_lds((const AS1 void*)g, (AS3 void*)l, 16, 0, 0);
}

// fp32 -> bf16 round-to-nearest-even (finite data)
__device__ __forceinline__ u16 f2bf(float f) {
  uint32_t u = __builtin_bit_cast(uint32_t, f);
  u += 0x7fffu + ((u >> 16) & 1u);
  return (u16)(u >> 16);
}

// ---------------- fused conversion kernel (3 tensors, fp32 -> bf16) ---------
__global__ void k_cvt3(const float* __restrict__ a, u16* __restrict__ ao, int na4,
                       const float* __restrict__ b, u16* __restrict__ bo, int nb4,
                       const float* __restrict__ c, u16* __restrict__ co, int nc4) {
  int i = blockIdx.x * 256 + threadIdx.x;
  const float* src;
  u16* dst;
  if (i < na4) {
    src = a; dst = ao;
  } else if (i < na4 + nb4) {
    src = b; dst = bo; i -= na4;
  } else if (i < na4 + nb4 + nc4) {
    src = c; dst = co; i -= na4 + nb4;
  } else {
    return;
  }
  f32x4v v = ((const f32x4v*)src)[i];
  u16x4 o;
  o.x = f2bf(v.x); o.y = f2bf(v.y); o.z = f2bf(v.z); o.w = f2bf(v.w);
  ((u16x4*)dst)[i] = o;
}

// ---------------- GEMM1: qkv = x @ w_in^T + b_in -> Q,K,V bf16 [B,H,L,64] ----
__global__ __launch_bounds__(256) void k_gemm_qkv(
    const u16* __restrict__ Xb, const u16* __restrict__ Wb,
    const float* __restrict__ b_in,
    u16* __restrict__ gQ, u16* __restrict__ gK, u16* __restrict__ gV) {
  __shared__ u16 As[128 * 64];
  __shared__ u16 Bs[128 * 64];
  const int tid = threadIdx.x;
  const int lane = tid & 63;
  const int w = tid >> 6;
  const int wm = (w >> 1) * 64;
  const int wn = (w & 1) * 64;
  const int lr = lane & 15;
  const int lg = lane >> 4;
  const int m0 = blockIdx.x * 128;
  const int n0 = blockIdx.y * 128;

  f32x4 acc[4][4];
#pragma unroll
  for (int i = 0; i < 4; ++i)
#pragma unroll
    for (int j = 0; j < 4; ++j) acc[i][j] = (f32x4){0.f, 0.f, 0.f, 0.f};

  for (int kt = 0; kt < 12; ++kt) {
    __syncthreads();
#pragma unroll
    for (int i = 0; i < 4; ++i) {
      int seg = i * 256 + tid;
      int row = seg >> 3;
      int sl = (seg & 7) ^ (row & 7);
      gll16(Xb + (size_t)(m0 + row) * 768 + kt * 64 + sl * 8, (char*)As + seg * 16);
      gll16(Wb + (size_t)(n0 + row) * 768 + kt * 64 + sl * 8, (char*)Bs + seg * 16);
    }
    __syncthreads();
#pragma unroll
    for (int kh = 0; kh < 2; ++kh) {
      bf16x8 af[4], bfr[4];
#pragma unroll
      for (int t = 0; t < 4; ++t) {
        int ra = wm + t * 16 + lr;
        af[t] = *(const bf16x8*)((const char*)As + ra * 128 +
                                 ((kh * 64 + lg * 16) ^ ((ra & 7) << 4)));
        int rb = wn + t * 16 + lr;
        bfr[t] = *(const bf16x8*)((const char*)Bs + rb * 128 +
                                  ((kh * 64 + lg * 16) ^ ((rb & 7) << 4)));
      }
#pragma unroll
      for (int mi = 0; mi < 4; ++mi)
#pragma unroll
        for (int ni = 0; ni < 4; ++ni)
          acc[mi][ni] = __builtin_amdgcn_mfma_f32_16x16x32_bf16(
              af[mi], bfr[ni], acc[mi][ni], 0, 0, 0);
    }
  }
  // epilogue: +b_in, scale q, scatter to [B,H,L,64] bf16
  const int sec = blockIdx.y / 6;  // 0=q,1=k,2=v
  u16* dst = sec == 0 ? gQ : (sec == 1 ? gK : gV);
  const float scale = sec == 0 ? 0.125f : 1.0f;
#pragma unroll
  for (int ni = 0; ni < 4; ++ni) {
    int e = n0 + wn + ni * 16 + lr;  // 0..2303
    float bias = b_in[e];
    int es = e - sec * 768;
    int h = es >> 6, d = es & 63;
#pragma unroll
    for (int mi = 0; mi < 4; ++mi) {
#pragma unroll
      for (int j = 0; j < 4; ++j) {
        int m = m0 + wm + mi * 16 + lg * 4 + j;
        int bb = m >> 10, lq = m & 1023;
        float vv = (acc[mi][ni][j] + bias) * scale;
        dst[(size_t)((bb * 12 + h) * 1024 + lq) * 64 + d] = f2bf(vv);
      }
    }
  }
}

// ---------------- V transpose: [B,H,L,64] -> [B,H,64,L] ---------------------
__global__ __launch_bounds__(256) void k_transpose(const u16* __restrict__ V,
                                                   u16* __restrict__ Vt) {
  __shared__ u16 t[64][66];
  const int tid = threadIdx.x;
  const int bh = blockIdx.x >> 4;
  const int kv0 = (blockIdx.x & 15) * 64;
  {
    int r = tid >> 2, c0 = (tid & 3) * 16;
    const u16* src = V + (size_t)(bh * 1024 + kv0 + r) * 64 + c0;
#pragma unroll
    for (int p = 0; p < 2; ++p) {
      u16x8 x = *(const u16x8*)(src + p * 8);
#pragma unroll
      for (int e = 0; e < 8; ++e) t[r][c0 + p * 8 + e] = x[e];
    }
  }
  __syncthreads();
  {
    int d = tid >> 2, k0 = (tid & 3) * 16;
    u16* dst = Vt + (size_t)(bh * 64 + d) * 1024 + kv0 + k0;
#pragma unroll
    for (int p = 0; p < 2; ++p) {
      u16x8 o;
#pragma unroll
      for (int e = 0; e < 8; ++e) o[e] = t[k0 + p * 8 + e][d];
      *(u16x8*)(dst + p * 8) = o;
    }
  }
}

// ---------------- fused flash attention (q128, pair-processed tiles) --------
// R10 body, but tiles processed in PAIRS: KV 4-deep buffered; both tiles of
// the next pair staged at the top of the current pair (2-tile latency cover);
// ONE barrier per pair (8 total instead of 16) -> halves the per-tile fixed
// cost (barrier join + drain stall) identified from the R9->R10 delta.
// Bias: two register sets, each reloaded right after its tile consumes it.
__global__ __launch_bounds__(256, 2) void k_attn(
    const u16* __restrict__ gQ, const u16* __restrict__ gK,
    const u16* __restrict__ gVt, const float* __restrict__ gBias,
    u16* __restrict__ gO) {
  __shared__ u16 Ks[4][64 * 64];  // 32 KB, 4-deep [kv][d] rows 128B
  __shared__ u16 Vs[4][64 * 64];  // 32 KB, 4-deep [d][kv]
  __shared__ f32x4 PlV[4][256];   // 16 KB: per-wave 4KB (2KB per subtile)
  const int tid = threadIdx.x;
  const int lane = tid & 63;
  const int w = tid >> 6;
  const int lr = lane & 15;
  const int lg = lane >> 4;
  // XCD-bijective swizzle: 384 = 8 XCDs x 48; the 8 q-blocks sharing one
  // (b,h)'s K/V land on one XCD -> K/V stay L2-resident.
  const int lb = (blockIdx.x & 7) * 48 + (blockIdx.x >> 3);
  const int bh = lb >> 3;
  const int q0 = (lb & 7) * 128;
  const int qr0 = q0 + w * 16;       // subtile 0 base
  const int qr1 = q0 + 64 + w * 16;  // subtile 1 base

#define STAGE_KV(buf, kv0)                                                     \
  do {                                                                         \
    _Pragma("unroll") for (int i_ = 0; i_ < 2; ++i_) {                         \
      int seg_ = i_ * 256 + tid;                                               \
      int row_ = seg_ >> 3;                                                    \
      int sl_ = (seg_ & 7) ^ (row_ & 7);                                       \
      gll16(gK + (size_t)(bh * 1024 + (kv0) + row_) * 64 + sl_ * 8,            \
            (char*)Ks[buf] + seg_ * 16);                                       \
      gll16(gVt + (size_t)(bh * 64 + row_) * 1024 + (kv0) + sl_ * 8,           \
            (char*)Vs[buf] + seg_ * 16);                                       \
    }                                                                          \
  } while (0)

  const float* bline0 = gBias + (size_t)(bh * 1024 + qr0 + lr) * 1024;
  const float* bline1 = gBias + (size_t)(bh * 1024 + qr1 + lr) * 1024;

#define BIAS_LOAD(dst, kv0)                                                    \
  do {                                                                         \
    _Pragma("unroll") for (int ni_ = 0; ni_ < 4; ++ni_) {                      \
      dst[0][ni_] = *(const f32x4*)(bline0 + (kv0) + ni_ * 16 + lg * 4);       \
      dst[1][ni_] = *(const f32x4*)(bline1 + (kv0) + ni_ * 16 + lg * 4);       \
    }                                                                          \
  } while (0)

  // Q as B-operand (pre-scaled by 1/8 in GEMM1)
  bf16x8 qa[2][2];
#pragma unroll
  for (int kh = 0; kh < 2; ++kh) {
    qa[0][kh] = *(const bf16x8*)(gQ + (size_t)(bh * 1024 + qr0 + lr) * 64 + kh * 32 + lg * 8);
    qa[1][kh] = *(const bf16x8*)(gQ + (size_t)(bh * 1024 + qr1 + lr) * 64 + kh * 32 + lg * 8);
  }

  f32x4 oacc[2][4];
#pragma unroll
  for (int p = 0; p < 2; ++p)
#pragma unroll
    for (int dt = 0; dt < 4; ++dt) oacc[p][dt] = (f32x4){0.f, 0.f, 0.f, 0.f};
  float mrow[2] = {-1e30f, -1e30f}, lrow[2] = {0.f, 0.f};

  char* plw = (char*)PlV[w];
  const int swz = (lr & 7) << 4;

  f32x4 b0[2][4], b1[2][4];

  // one tile's full body (QK^T + bias + softmax + P + PV) on buffer `cur`
  auto tile_body = [&](int cur, f32x4 (&bc)[2][4]) {
    f32x4 s[2][4];
#pragma unroll
    for (int p = 0; p < 2; ++p)
#pragma unroll
      for (int ni = 0; ni < 4; ++ni) s[p][ni] = (f32x4){0.f, 0.f, 0.f, 0.f};
    __builtin_amdgcn_s_setprio(1);
#pragma unroll
    for (int kh = 0; kh < 2; ++kh)
#pragma unroll
      for (int ni = 0; ni < 4; ++ni) {
        int rk = ni * 16 + lr;
        bf16x8 kb = *(const bf16x8*)((const char*)Ks[cur] + rk * 128 +
                                     ((kh * 64 + lg * 16) ^ ((rk & 7) << 4)));
        s[0][ni] = __builtin_amdgcn_mfma_f32_16x16x32_bf16(kb, qa[0][kh], s[0][ni], 0, 0, 0);
        s[1][ni] = __builtin_amdgcn_mfma_f32_16x16x32_bf16(kb, qa[1][kh], s[1][ni], 0, 0, 0);
      }
    __builtin_amdgcn_s_setprio(0);

#pragma unroll
    for (int ni = 0; ni < 4; ++ni) {
      s[0][ni] += bc[0][ni];
      s[1][ni] += bc[1][ni];
    }

#pragma unroll
    for (int p = 0; p < 2; ++p) {
      float mx0 = fmaxf(fmaxf(s[p][0][0], s[p][0][1]), fmaxf(s[p][0][2], s[p][0][3]));
      float mx1 = fmaxf(fmaxf(s[p][1][0], s[p][1][1]), fmaxf(s[p][1][2], s[p][1][3]));
      float mx2 = fmaxf(fmaxf(s[p][2][0], s[p][2][1]), fmaxf(s[p][2][2], s[p][2][3]));
      float mx3 = fmaxf(fmaxf(s[p][3][0], s[p][3][1]), fmaxf(s[p][3][2], s[p][3][3]));
      float vmax = fmaxf(fmaxf(mx0, mx1), fmaxf(mx2, mx3));
      vmax = fmaxf(vmax, __shfl_xor(vmax, 16));
      vmax = fmaxf(vmax, __shfl_xor(vmax, 32));
      float mnew = fmaxf(mrow[p], vmax);
      float al = __expf(mrow[p] - mnew);
      mrow[p] = mnew;
#pragma unroll
      for (int ni = 0; ni < 4; ++ni)
#pragma unroll
        for (int j = 0; j < 4; ++j) s[p][ni][j] = __expf(s[p][ni][j] - mnew);
      float r0 = (s[p][0][0] + s[p][0][1]) + (s[p][0][2] + s[p][0][3]);
      float r1 = (s[p][1][0] + s[p][1][1]) + (s[p][1][2] + s[p][1][3]);
      float r2 = (s[p][2][0] + s[p][2][1]) + (s[p][2][2] + s[p][2][3]);
      float r3 = (s[p][3][0] + s[p][3][1]) + (s[p][3][2] + s[p][3][3]);
      float rs = (r0 + r1) + (r2 + r3);
      rs += __shfl_xor(rs, 16);
      rs += __shfl_xor(rs, 32);
      lrow[p] = lrow[p] * al + rs;
      f32x4 av;
#pragma unroll
      for (int j = 0; j < 4; ++j) av[j] = __shfl(al, (lane & 48) | (lg * 4 + j));
#pragma unroll
      for (int dt = 0; dt < 4; ++dt) oacc[p][dt] *= av;
    }

#pragma unroll
    for (int p = 0; p < 2; ++p) {
      char* pl = plw + p * 2048;
#pragma unroll
      for (int ni = 0; ni < 4; ++ni) {
        uint32_t w0 = (uint32_t)f2bf(s[p][ni][0]) | ((uint32_t)f2bf(s[p][ni][1]) << 16);
        uint32_t w1 = (uint32_t)f2bf(s[p][ni][2]) | ((uint32_t)f2bf(s[p][ni][3]) << 16);
        u32x2 pv = {w0, w1};
        *(u32x2*)(pl + lr * 128 + ((ni * 32 + lg * 8) ^ swz)) = pv;
      }
    }
    __builtin_amdgcn_s_setprio(1);
#pragma unroll
    for (int kh = 0; kh < 2; ++kh) {
      bf16x8 pa0 = *(const bf16x8*)(plw + lr * 128 + ((kh * 64 + lg * 16) ^ swz));
      bf16x8 pa1 = *(const bf16x8*)(plw + 2048 + lr * 128 + ((kh * 64 + lg * 16) ^ swz));
#pragma unroll
      for (int dt = 0; dt < 4; ++dt) {
        int rv = dt * 16 + lr;
        bf16x8 vb = *(const bf16x8*)((const char*)Vs[cur] + rv * 128 +
                                     ((kh * 64 + lg * 16) ^ ((rv & 7) << 4)));
        oacc[0][dt] = __builtin_amdgcn_mfma_f32_16x16x32_bf16(pa0, vb, oacc[0][dt], 0, 0, 0);
        oacc[1][dt] = __builtin_amdgcn_mfma_f32_16x16x32_bf16(pa1, vb, oacc[1][dt], 0, 0, 0);
      }
    }
    __builtin_amdgcn_s_setprio(0);
  };

  // prologue: stage pair 0 (tiles 0,1); load their bias
  STAGE_KV(0, 0);
  STAGE_KV(1, 64);
  BIAS_LOAD(b0, 0);
  BIAS_LOAD(b1, 64);
  __syncthreads();

  for (int i = 0; i < 8; ++i) {
    const int t0 = 2 * i;
    if (i < 7) {                       // stage next pair: 2-tile latency cover
      STAGE_KV((t0 + 2) & 3, (t0 + 2) * 64);
      STAGE_KV((t0 + 3) & 3, (t0 + 3) * 64);
    }
    tile_body(t0 & 3, b0);
    if (i < 7) BIAS_LOAD(b0, (t0 + 2) * 64);
    tile_body((t0 + 1) & 3, b1);
    if (i < 7) {
      BIAS_LOAD(b1, (t0 + 3) * 64);
      __syncthreads();                 // ONE barrier per pair (drains stages+bias)
    }
  }

  // normalize + store O bf16 [B,L,D]
  const int bg = bh / 12, h = bh % 12;
#pragma unroll
  for (int p = 0; p < 2; ++p) {
    float inv = 1.0f / lrow[p];
    f32x4 iv;
#pragma unroll
    for (int j = 0; j < 4; ++j) iv[j] = __shfl(inv, (lane & 48) | (lg * 4 + j));
    const int qrp = p == 0 ? qr0 : qr1;
#pragma unroll
    for (int j = 0; j < 4; ++j) {
      int row = qrp + lg * 4 + j;
#pragma unroll
      for (int dt = 0; dt < 4; ++dt) {
        gO[(size_t)(bg * 1024 + row) * 768 + h * 64 + dt * 16 + lr] =
            f2bf(oacc[p][dt][j] * iv[j]);
      }
    }
  }
#undef STAGE_KV
#undef BIAS_LOAD
}

// ---------------- GEMM2: out = O @ w_out^T + b_out (fp32 out), 64x64 tiles --
__global__ __launch_bounds__(256) void k_gemm_out(
    const u16* __restrict__ Ob, const u16* __restrict__ Wb,
    const float* __restrict__ b_out, float* __restrict__ out) {
  __shared__ u16 As[64 * 64];
  __shared__ u16 Bs[64 * 64];
  const int tid = threadIdx.x;
  const int lane = tid & 63;
  const int w = tid >> 6;
  const int wm = (w >> 1) * 32;
  const int wn = (w & 1) * 32;
  const int lr = lane & 15;
  const int lg = lane >> 4;
  const int m0 = blockIdx.x * 64;
  const int n0 = blockIdx.y * 64;

  f32x4 acc[2][2];
#pragma unroll
  for (int i = 0; i < 2; ++i)
#pragma unroll
    for (int j = 0; j < 2; ++j) acc[i][j] = (f32x4){0.f, 0.f, 0.f, 0.f};

  for (int kt = 0; kt < 12; ++kt) {
    __syncthreads();
#pragma unroll
    for (int i = 0; i < 2; ++i) {
      int seg = i * 256 + tid;
      int row = seg >> 3;
      int sl = (seg & 7) ^ (row & 7);
      gll16(Ob + (size_t)(m0 + row) * 768 + kt * 64 + sl * 8, (char*)As + seg * 16);
      gll16(Wb + (size_t)(n0 + row) * 768 + kt * 64 + sl * 8, (char*)Bs + seg * 16);
    }
    __syncthreads();
#pragma unroll
    for (int kh = 0; kh < 2; ++kh) {
      bf16x8 af[2], bfr[2];
#pragma unroll
      for (int t = 0; t < 2; ++t) {
        int ra = wm + t * 16 + lr;
        af[t] = *(const bf16x8*)((const char*)As + ra * 128 +
                                 ((kh * 64 + lg * 16) ^ ((ra & 7) << 4)));
        int rb = wn + t * 16 + lr;
        bfr[t] = *(const bf16x8*)((const char*)Bs + rb * 128 +
                                  ((kh * 64 + lg * 16) ^ ((rb & 7) << 4)));
      }
#pragma unroll
      for (int mi = 0; mi < 2; ++mi)
#pragma unroll
        for (int ni = 0; ni < 2; ++ni)
          acc[mi][ni] = __builtin_amdgcn_mfma_f32_16x16x32_bf16(
              af[mi], bfr[ni], acc[mi][ni], 0, 0, 0);
    }
  }
#pragma unroll
  for (int ni = 0; ni < 2; ++ni) {
    int n = n0 + wn + ni * 16 + lr;
    float bias = b_out[n];
#pragma unroll
    for (int mi = 0; mi < 2; ++mi) {
#pragma unroll
      for (int j = 0; j < 4; ++j) {
        int m = m0 + wm + mi * 16 + lg * 4 + j;
        out[(size_t)m * 768 + n] = acc[mi][ni][j] + bias;
      }
    }
  }
}

extern "C" void kernel_launch(void* const* d_in, const int* in_sizes, int n_in,
                              void* d_out, int out_size, void* d_ws, size_t ws_size,
                              hipStream_t stream) {
  const float* x = (const float*)d_in[0];
  const float* attn_bias = (const float*)d_in[1];
  const float* w_in = (const float*)d_in[2];
  const float* b_in = (const float*)d_in[3];
  const float* w_out = (const float*)d_in[4];
  const float* b_out = (const float*)d_in[5];
  float* out = (float*)d_out;

  char* ws = (char*)d_ws;
  size_t off = 0;
  u16* xb = (u16*)(ws + off);  off += (size_t)M_ * D_ * 2;
  u16* wib = (u16*)(ws + off); off += (size_t)N3_ * D_ * 2;
  u16* wob = (u16*)(ws + off); off += (size_t)D_ * D_ * 2;
  u16* q = (u16*)(ws + off);   off += (size_t)48 * 1024 * 64 * 2;
  u16* k = (u16*)(ws + off);   off += (size_t)48 * 1024 * 64 * 2;
  u16* v = (u16*)(ws + off);   off += (size_t)48 * 1024 * 64 * 2;
  u16* vt = (u16*)(ws + off);  off += (size_t)48 * 1024 * 64 * 2;
  u16* ob = (u16*)(ws + off);  off += (size_t)M_ * D_ * 2;

  const int na4 = (M_ * D_) / 4;
  const int nb4 = (N3_ * D_) / 4;
  const int nc4 = (D_ * D_) / 4;
  k_cvt3<<<(na4 + nb4 + nc4 + 255) / 256, 256, 0, stream>>>(
      x, xb, na4, w_in, wib, nb4, w_out, wob, nc4);
  k_gemm_qkv<<<dim3(32, 18), 256, 0, stream>>>(xb, wib, b_in, q, k, v);
  k_transpose<<<768, 256, 0, stream>>>(v, vt);
  k_attn<<<384, 256, 0, stream>>>(q, k, vt, attn_bias, ob);
  k_gemm_out<<<dim3(64, 12), 256, 0, stream>>>(ob, wob, b_out, out);
}

// Round 12
// 110.555 us; speedup vs baseline: 1.4445x; 1.0341x over previous
//
#include <hip/hip_runtime.h>
#include <hip/hip_bf16.h>
#include <stdint.h>

// Problem constants
#define B_ 4
#define L_ 1024
#define D_ 768
#define H_ 12
#define HD_ 64
#define M_ 4096     // B*L
#define N3_ 2304    // 3*D

typedef float f32x4 __attribute__((ext_vector_type(4)));
typedef float f32x4v __attribute__((ext_vector_type(4)));
typedef short bf16x8 __attribute__((ext_vector_type(8)));
typedef unsigned short u16;
typedef u16 u16x8 __attribute__((ext_vector_type(8)));
typedef u16 u16x4 __attribute__((ext_vector_type(4)));
typedef uint32_t u32x2 __attribute__((ext_vector_type(2)));

#define AS3 __attribute__((address_space(3)))
#define AS1 __attribute__((address_space(1)))

__device__ __forceinline__ void gll16(const void* g, void* l) {
  __builtin_amdgcn_global_load_lds((const AS1 void*)g, (AS3 void*)l, 16, 0, 0);
}

// fp32 -> bf16 round-to-nearest-even (finite data)
__device__ __forceinline__ u16 f2bf(float f) {
  uint32_t u = __builtin_bit_cast(uint32_t, f);
  u += 0x7fffu + ((u >> 16) & 1u);
  return (u16)(u >> 16);
}

// ---------------- fused conversion kernel (3 tensors, fp32 -> bf16) ---------
__global__ void k_cvt3(const float* __restrict__ a, u16* __restrict__ ao, int na4,
                       const float* __restrict__ b, u16* __restrict__ bo, int nb4,
                       const float* __restrict__ c, u16* __restrict__ co, int nc4) {
  int i = blockIdx.x * 256 + threadIdx.x;
  const float* src;
  u16* dst;
  if (i < na4) {
    src = a; dst = ao;
  } else if (i < na4 + nb4) {
    src = b; dst = bo; i -= na4;
  } else if (i < na4 + nb4 + nc4) {
    src = c; dst = co; i -= na4 + nb4;
  } else {
    return;
  }
  f32x4v v = ((const f32x4v*)src)[i];
  u16x4 o;
  o.x = f2bf(v.x); o.y = f2bf(v.y); o.z = f2bf(v.z); o.w = f2bf(v.w);
  ((u16x4*)dst)[i] = o;
}

// ---------------- GEMM1: qkv = x @ w_in^T + b_in -----------------------------
// -> Q,K bf16 [B,H,L,64]; V written TRANSPOSED directly as Vt [B,H,64,L]
// (acc j-index = consecutive lq = contiguous in Vt rows -> u16x4 stores;
//  this fuses the old k_transpose kernel for free).
__global__ __launch_bounds__(256) void k_gemm_qkv(
    const u16* __restrict__ Xb, const u16* __restrict__ Wb,
    const float* __restrict__ b_in,
    u16* __restrict__ gQ, u16* __restrict__ gK, u16* __restrict__ gVt) {
  __shared__ u16 As[128 * 64];
  __shared__ u16 Bs[128 * 64];
  const int tid = threadIdx.x;
  const int lane = tid & 63;
  const int w = tid >> 6;
  const int wm = (w >> 1) * 64;
  const int wn = (w & 1) * 64;
  const int lr = lane & 15;
  const int lg = lane >> 4;
  const int m0 = blockIdx.x * 128;
  const int n0 = blockIdx.y * 128;

  f32x4 acc[4][4];
#pragma unroll
  for (int i = 0; i < 4; ++i)
#pragma unroll
    for (int j = 0; j < 4; ++j) acc[i][j] = (f32x4){0.f, 0.f, 0.f, 0.f};

  for (int kt = 0; kt < 12; ++kt) {
    __syncthreads();
#pragma unroll
    for (int i = 0; i < 4; ++i) {
      int seg = i * 256 + tid;
      int row = seg >> 3;
      int sl = (seg & 7) ^ (row & 7);
      gll16(Xb + (size_t)(m0 + row) * 768 + kt * 64 + sl * 8, (char*)As + seg * 16);
      gll16(Wb + (size_t)(n0 + row) * 768 + kt * 64 + sl * 8, (char*)Bs + seg * 16);
    }
    __syncthreads();
#pragma unroll
    for (int kh = 0; kh < 2; ++kh) {
      bf16x8 af[4], bfr[4];
#pragma unroll
      for (int t = 0; t < 4; ++t) {
        int ra = wm + t * 16 + lr;
        af[t] = *(const bf16x8*)((const char*)As + ra * 128 +
                                 ((kh * 64 + lg * 16) ^ ((ra & 7) << 4)));
        int rb = wn + t * 16 + lr;
        bfr[t] = *(const bf16x8*)((const char*)Bs + rb * 128 +
                                  ((kh * 64 + lg * 16) ^ ((rb & 7) << 4)));
      }
#pragma unroll
      for (int mi = 0; mi < 4; ++mi)
#pragma unroll
        for (int ni = 0; ni < 4; ++ni)
          acc[mi][ni] = __builtin_amdgcn_mfma_f32_16x16x32_bf16(
              af[mi], bfr[ni], acc[mi][ni], 0, 0, 0);
    }
  }
  const int sec = blockIdx.y / 6;  // 0=q,1=k,2=v
  if (sec == 2) {
    // V: write transposed (Vt[bh][d][lq]); j-run of 4 lq is contiguous -> 8B
#pragma unroll
    for (int ni = 0; ni < 4; ++ni) {
      int e = n0 + wn + ni * 16 + lr;
      float bias = b_in[e];
      int es = e - 1536;
      int h = es >> 6, d = es & 63;
#pragma unroll
      for (int mi = 0; mi < 4; ++mi) {
        int m = m0 + wm + mi * 16 + lg * 4;
        int bb = m >> 10, lq = m & 1023;
        u16x4 o;
#pragma unroll
        for (int j = 0; j < 4; ++j) o[j] = f2bf(acc[mi][ni][j] + bias);
        *(u16x4*)(gVt + (size_t)((bb * 12 + h) * 64 + d) * 1024 + lq) = o;
      }
    }
  } else {
    u16* dst = sec == 0 ? gQ : gK;
    const float scale = sec == 0 ? 0.125f : 1.0f;
#pragma unroll
    for (int ni = 0; ni < 4; ++ni) {
      int e = n0 + wn + ni * 16 + lr;
      float bias = b_in[e];
      int es = e - sec * 768;
      int h = es >> 6, d = es & 63;
#pragma unroll
      for (int mi = 0; mi < 4; ++mi) {
#pragma unroll
        for (int j = 0; j < 4; ++j) {
          int m = m0 + wm + mi * 16 + lg * 4 + j;
          int bb = m >> 10, lq = m & 1023;
          float vv = (acc[mi][ni][j] + bias) * scale;
          dst[(size_t)((bb * 12 + h) * 1024 + lq) * 64 + d] = f2bf(vv);
        }
      }
    }
  }
}

// ---------------- fused flash attention (q128, pair-processed tiles) --------
// At the measured platform wall: bias fp32 (192MB) crossing the L3->L2 fill
// path at ~2.7 TB/s sets ~72us regardless of pipelining (R1-R11 evidence).
// Structure: q-tile 128 (2 subtiles/wave), KV 4-deep gll16 double-pair
// buffering, one barrier per tile-pair, register bias depth-1.5.
__global__ __launch_bounds__(256, 2) void k_attn(
    const u16* __restrict__ gQ, const u16* __restrict__ gK,
    const u16* __restrict__ gVt, const float* __restrict__ gBias,
    u16* __restrict__ gO) {
  __shared__ u16 Ks[4][64 * 64];  // 32 KB, 4-deep [kv][d] rows 128B
  __shared__ u16 Vs[4][64 * 64];  // 32 KB, 4-deep [d][kv]
  __shared__ f32x4 PlV[4][256];   // 16 KB: per-wave 4KB (2KB per subtile)
  const int tid = threadIdx.x;
  const int lane = tid & 63;
  const int w = tid >> 6;
  const int lr = lane & 15;
  const int lg = lane >> 4;
  // XCD-bijective swizzle: 384 = 8 XCDs x 48
  const int lb = (blockIdx.x & 7) * 48 + (blockIdx.x >> 3);
  const int bh = lb >> 3;
  const int q0 = (lb & 7) * 128;
  const int qr0 = q0 + w * 16;
  const int qr1 = q0 + 64 + w * 16;

#define STAGE_KV(buf, kv0)                                                     \
  do {                                                                         \
    _Pragma("unroll") for (int i_ = 0; i_ < 2; ++i_) {                         \
      int seg_ = i_ * 256 + tid;                                               \
      int row_ = seg_ >> 3;                                                    \
      int sl_ = (seg_ & 7) ^ (row_ & 7);                                       \
      gll16(gK + (size_t)(bh * 1024 + (kv0) + row_) * 64 + sl_ * 8,            \
            (char*)Ks[buf] + seg_ * 16);                                       \
      gll16(gVt + (size_t)(bh * 64 + row_) * 1024 + (kv0) + sl_ * 8,           \
            (char*)Vs[buf] + seg_ * 16);                                       \
    }                                                                          \
  } while (0)

  const float* bline0 = gBias + (size_t)(bh * 1024 + qr0 + lr) * 1024;
  const float* bline1 = gBias + (size_t)(bh * 1024 + qr1 + lr) * 1024;

#define BIAS_LOAD(dst, kv0)                                                    \
  do {                                                                         \
    _Pragma("unroll") for (int ni_ = 0; ni_ < 4; ++ni_) {                      \
      dst[0][ni_] = *(const f32x4*)(bline0 + (kv0) + ni_ * 16 + lg * 4);       \
      dst[1][ni_] = *(const f32x4*)(bline1 + (kv0) + ni_ * 16 + lg * 4);       \
    }                                                                          \
  } while (0)

  bf16x8 qa[2][2];
#pragma unroll
  for (int kh = 0; kh < 2; ++kh) {
    qa[0][kh] = *(const bf16x8*)(gQ + (size_t)(bh * 1024 + qr0 + lr) * 64 + kh * 32 + lg * 8);
    qa[1][kh] = *(const bf16x8*)(gQ + (size_t)(bh * 1024 + qr1 + lr) * 64 + kh * 32 + lg * 8);
  }

  f32x4 oacc[2][4];
#pragma unroll
  for (int p = 0; p < 2; ++p)
#pragma unroll
    for (int dt = 0; dt < 4; ++dt) oacc[p][dt] = (f32x4){0.f, 0.f, 0.f, 0.f};
  float mrow[2] = {-1e30f, -1e30f}, lrow[2] = {0.f, 0.f};

  char* plw = (char*)PlV[w];
  const int swz = (lr & 7) << 4;

  f32x4 b0[2][4], b1[2][4];

  auto tile_body = [&](int cur, f32x4 (&bc)[2][4]) {
    f32x4 s[2][4];
#pragma unroll
    for (int p = 0; p < 2; ++p)
#pragma unroll
      for (int ni = 0; ni < 4; ++ni) s[p][ni] = (f32x4){0.f, 0.f, 0.f, 0.f};
    __builtin_amdgcn_s_setprio(1);
#pragma unroll
    for (int kh = 0; kh < 2; ++kh)
#pragma unroll
      for (int ni = 0; ni < 4; ++ni) {
        int rk = ni * 16 + lr;
        bf16x8 kb = *(const bf16x8*)((const char*)Ks[cur] + rk * 128 +
                                     ((kh * 64 + lg * 16) ^ ((rk & 7) << 4)));
        s[0][ni] = __builtin_amdgcn_mfma_f32_16x16x32_bf16(kb, qa[0][kh], s[0][ni], 0, 0, 0);
        s[1][ni] = __builtin_amdgcn_mfma_f32_16x16x32_bf16(kb, qa[1][kh], s[1][ni], 0, 0, 0);
      }
    __builtin_amdgcn_s_setprio(0);

#pragma unroll
    for (int ni = 0; ni < 4; ++ni) {
      s[0][ni] += bc[0][ni];
      s[1][ni] += bc[1][ni];
    }

#pragma unroll
    for (int p = 0; p < 2; ++p) {
      float mx0 = fmaxf(fmaxf(s[p][0][0], s[p][0][1]), fmaxf(s[p][0][2], s[p][0][3]));
      float mx1 = fmaxf(fmaxf(s[p][1][0], s[p][1][1]), fmaxf(s[p][1][2], s[p][1][3]));
      float mx2 = fmaxf(fmaxf(s[p][2][0], s[p][2][1]), fmaxf(s[p][2][2], s[p][2][3]));
      float mx3 = fmaxf(fmaxf(s[p][3][0], s[p][3][1]), fmaxf(s[p][3][2], s[p][3][3]));
      float vmax = fmaxf(fmaxf(mx0, mx1), fmaxf(mx2, mx3));
      vmax = fmaxf(vmax, __shfl_xor(vmax, 16));
      vmax = fmaxf(vmax, __shfl_xor(vmax, 32));
      float mnew = fmaxf(mrow[p], vmax);
      float al = __expf(mrow[p] - mnew);
      mrow[p] = mnew;
#pragma unroll
      for (int ni = 0; ni < 4; ++ni)
#pragma unroll
        for (int j = 0; j < 4; ++j) s[p][ni][j] = __expf(s[p][ni][j] - mnew);
      float r0 = (s[p][0][0] + s[p][0][1]) + (s[p][0][2] + s[p][0][3]);
      float r1 = (s[p][1][0] + s[p][1][1]) + (s[p][1][2] + s[p][1][3]);
      float r2 = (s[p][2][0] + s[p][2][1]) + (s[p][2][2] + s[p][2][3]);
      float r3 = (s[p][3][0] + s[p][3][1]) + (s[p][3][2] + s[p][3][3]);
      float rs = (r0 + r1) + (r2 + r3);
      rs += __shfl_xor(rs, 16);
      rs += __shfl_xor(rs, 32);
      lrow[p] = lrow[p] * al + rs;
      f32x4 av;
#pragma unroll
      for (int j = 0; j < 4; ++j) av[j] = __shfl(al, (lane & 48) | (lg * 4 + j));
#pragma unroll
      for (int dt = 0; dt < 4; ++dt) oacc[p][dt] *= av;
    }

#pragma unroll
    for (int p = 0; p < 2; ++p) {
      char* pl = plw + p * 2048;
#pragma unroll
      for (int ni = 0; ni < 4; ++ni) {
        uint32_t w0 = (uint32_t)f2bf(s[p][ni][0]) | ((uint32_t)f2bf(s[p][ni][1]) << 16);
        uint32_t w1 = (uint32_t)f2bf(s[p][ni][2]) | ((uint32_t)f2bf(s[p][ni][3]) << 16);
        u32x2 pv = {w0, w1};
        *(u32x2*)(pl + lr * 128 + ((ni * 32 + lg * 8) ^ swz)) = pv;
      }
    }
    __builtin_amdgcn_s_setprio(1);
#pragma unroll
    for (int kh = 0; kh < 2; ++kh) {
      bf16x8 pa0 = *(const bf16x8*)(plw + lr * 128 + ((kh * 64 + lg * 16) ^ swz));
      bf16x8 pa1 = *(const bf16x8*)(plw + 2048 + lr * 128 + ((kh * 64 + lg * 16) ^ swz));
#pragma unroll
      for (int dt = 0; dt < 4; ++dt) {
        int rv = dt * 16 + lr;
        bf16x8 vb = *(const bf16x8*)((const char*)Vs[cur] + rv * 128 +
                                     ((kh * 64 + lg * 16) ^ ((rv & 7) << 4)));
        oacc[0][dt] = __builtin_amdgcn_mfma_f32_16x16x32_bf16(pa0, vb, oacc[0][dt], 0, 0, 0);
        oacc[1][dt] = __builtin_amdgcn_mfma_f32_16x16x32_bf16(pa1, vb, oacc[1][dt], 0, 0, 0);
      }
    }
    __builtin_amdgcn_s_setprio(0);
  };

  STAGE_KV(0, 0);
  STAGE_KV(1, 64);
  BIAS_LOAD(b0, 0);
  BIAS_LOAD(b1, 64);
  __syncthreads();

  for (int i = 0; i < 8; ++i) {
    const int t0 = 2 * i;
    if (i < 7) {
      STAGE_KV((t0 + 2) & 3, (t0 + 2) * 64);
      STAGE_KV((t0 + 3) & 3, (t0 + 3) * 64);
    }
    tile_body(t0 & 3, b0);
    if (i < 7) BIAS_LOAD(b0, (t0 + 2) * 64);
    tile_body((t0 + 1) & 3, b1);
    if (i < 7) {
      BIAS_LOAD(b1, (t0 + 3) * 64);
      __syncthreads();
    }
  }

  const int bg = bh / 12, h = bh % 12;
#pragma unroll
  for (int p = 0; p < 2; ++p) {
    float inv = 1.0f / lrow[p];
    f32x4 iv;
#pragma unroll
    for (int j = 0; j < 4; ++j) iv[j] = __shfl(inv, (lane & 48) | (lg * 4 + j));
    const int qrp = p == 0 ? qr0 : qr1;
#pragma unroll
    for (int j = 0; j < 4; ++j) {
      int row = qrp + lg * 4 + j;
#pragma unroll
      for (int dt = 0; dt < 4; ++dt) {
        gO[(size_t)(bg * 1024 + row) * 768 + h * 64 + dt * 16 + lr] =
            f2bf(oacc[p][dt][j] * iv[j]);
      }
    }
  }
#undef STAGE_KV
#undef BIAS_LOAD
}

// ---------------- GEMM2: out = O @ w_out^T + b_out (fp32 out), 64x64 tiles --
__global__ __launch_bounds__(256) void k_gemm_out(
    const u16* __restrict__ Ob, const u16* __restrict__ Wb,
    const float* __restrict__ b_out, float* __restrict__ out) {
  __shared__ u16 As[64 * 64];
  __shared__ u16 Bs[64 * 64];
  const int tid = threadIdx.x;
  const int lane = tid & 63;
  const int w = tid >> 6;
  const int wm = (w >> 1) * 32;
  const int wn = (w & 1) * 32;
  const int lr = lane & 15;
  const int lg = lane >> 4;
  const int m0 = blockIdx.x * 64;
  const int n0 = blockIdx.y * 64;

  f32x4 acc[2][2];
#pragma unroll
  for (int i = 0; i < 2; ++i)
#pragma unroll
    for (int j = 0; j < 2; ++j) acc[i][j] = (f32x4){0.f, 0.f, 0.f, 0.f};

  for (int kt = 0; kt < 12; ++kt) {
    __syncthreads();
#pragma unroll
    for (int i = 0; i < 2; ++i) {
      int seg = i * 256 + tid;
      int row = seg >> 3;
      int sl = (seg & 7) ^ (row & 7);
      gll16(Ob + (size_t)(m0 + row) * 768 + kt * 64 + sl * 8, (char*)As + seg * 16);
      gll16(Wb + (size_t)(n0 + row) * 768 + kt * 64 + sl * 8, (char*)Bs + seg * 16);
    }
    __syncthreads();
#pragma unroll
    for (int kh = 0; kh < 2; ++kh) {
      bf16x8 af[2], bfr[2];
#pragma unroll
      for (int t = 0; t < 2; ++t) {
        int ra = wm + t * 16 + lr;
        af[t] = *(const bf16x8*)((const char*)As + ra * 128 +
                                 ((kh * 64 + lg * 16) ^ ((ra & 7) << 4)));
        int rb = wn + t * 16 + lr;
        bfr[t] = *(const bf16x8*)((const char*)Bs + rb * 128 +
                                  ((kh * 64 + lg * 16) ^ ((rb & 7) << 4)));
      }
#pragma unroll
      for (int mi = 0; mi < 2; ++mi)
#pragma unroll
        for (int ni = 0; ni < 2; ++ni)
          acc[mi][ni] = __builtin_amdgcn_mfma_f32_16x16x32_bf16(
              af[mi], bfr[ni], acc[mi][ni], 0, 0, 0);
    }
  }
#pragma unroll
  for (int ni = 0; ni < 2; ++ni) {
    int n = n0 + wn + ni * 16 + lr;
    float bias = b_out[n];
#pragma unroll
    for (int mi = 0; mi < 2; ++mi) {
#pragma unroll
      for (int j = 0; j < 4; ++j) {
        int m = m0 + wm + mi * 16 + lg * 4 + j;
        out[(size_t)m * 768 + n] = acc[mi][ni][j] + bias;
      }
    }
  }
}

extern "C" void kernel_launch(void* const* d_in, const int* in_sizes, int n_in,
                              void* d_out, int out_size, void* d_ws, size_t ws_size,
                              hipStream_t stream) {
  const float* x = (const float*)d_in[0];
  const float* attn_bias = (const float*)d_in[1];
  const float* w_in = (const float*)d_in[2];
  const float* b_in = (const float*)d_in[3];
  const float* w_out = (const float*)d_in[4];
  const float* b_out = (const float*)d_in[5];
  float* out = (float*)d_out;

  char* ws = (char*)d_ws;
  size_t off = 0;
  u16* xb = (u16*)(ws + off);  off += (size_t)M_ * D_ * 2;
  u16* wib = (u16*)(ws + off); off += (size_t)N3_ * D_ * 2;
  u16* wob = (u16*)(ws + off); off += (size_t)D_ * D_ * 2;
  u16* q = (u16*)(ws + off);   off += (size_t)48 * 1024 * 64 * 2;
  u16* k = (u16*)(ws + off);   off += (size_t)48 * 1024 * 64 * 2;
  u16* vt = (u16*)(ws + off);  off += (size_t)48 * 1024 * 64 * 2;
  u16* ob = (u16*)(ws + off);  off += (size_t)M_ * D_ * 2;

  const int na4 = (M_ * D_) / 4;
  const int nb4 = (N3_ * D_) / 4;
  const int nc4 = (D_ * D_) / 4;
  k_cvt3<<<(na4 + nb4 + nc4 + 255) / 256, 256, 0, stream>>>(
      x, xb, na4, w_in, wib, nb4, w_out, wob, nc4);
  k_gemm_qkv<<<dim3(32, 18), 256, 0, stream>>>(xb, wib, b_in, q, k, vt);
  k_attn<<<384, 256, 0, stream>>>(q, k, vt, attn_bias, ob);
  k_gemm_out<<<dim3(64, 12), 256, 0, stream>>>(ob, wob, b_out, out);
}